// Round 6
// baseline (3154.684 us; speedup 1.0000x reference)
//
#include <hip/hip_runtime.h>

typedef unsigned short u16;
typedef unsigned int   u32;

#define TPB 512
#define RR  3
#define NIN 40

struct PtrTab { const void* p[NIN]; int n[NIN]; };

__device__ __forceinline__ float bf2f(u16 u){ union{u32 i; float f;} z; z.i = ((u32)u) << 16; return z.f; }
__device__ __forceinline__ u16 f2bf(float f){ union{float f; u32 i;} z; z.f = f; u32 u = z.i; return (u16)((u + 0x7fffu + ((u >> 16) & 1u)) >> 16); }
__device__ __forceinline__ float eluf(float x){ return x > 0.f ? x : (__expf(x) - 1.f); }
__device__ __forceinline__ float sigmf(float x){ return 1.f / (1.f + __expf(-x)); }

__device__ __forceinline__ float ldv(const void* p, int i, bool BF){
  if (BF){ return bf2f(((const u16*)p)[i]); }
  return ((const float*)p)[i];
}
__device__ __forceinline__ void ld8(const void* p, int i, bool BF, float* f){
  if (BF){
    uint4 w = *(const uint4*)(const void*)((const u16*)p + i);
    union{u32 i; float v;} t;
    t.i = w.x << 16; f[0] = t.v;  t.i = w.x & 0xffff0000u; f[1] = t.v;
    t.i = w.y << 16; f[2] = t.v;  t.i = w.y & 0xffff0000u; f[3] = t.v;
    t.i = w.z << 16; f[4] = t.v;  t.i = w.z & 0xffff0000u; f[5] = t.v;
    t.i = w.w << 16; f[6] = t.v;  t.i = w.w & 0xffff0000u; f[7] = t.v;
  } else {
    const float4* q = (const float4*)(const void*)((const float*)p + i);
    float4 a = q[0], b = q[1];
    f[0]=a.x; f[1]=a.y; f[2]=a.z; f[3]=a.w; f[4]=b.x; f[5]=b.y; f[6]=b.z; f[7]=b.w;
  }
}

// incoming neighbors of node n in the bidirectional kinematic tree
__device__ __forceinline__ int nbr_cnt(int n){ return n == 0 ? 4 : (n <= 8 ? 2 : 1); }
__device__ __forceinline__ int nbr_of(int n, int e){
  if (n == 0) return 1 + e;
  if (n <= 4) return e == 0 ? 0 : n + 4;
  if (n <= 8) return e == 0 ? n - 4 : n + 4;
  return n - 4;
}

// ---- per-input dtype probe: block i classifies input i (1=bf16, 0=f32) ----
__global__ __launch_bounds__(256) void probe_kernel(PtrTab T, int* fl){
  const int i = blockIdx.x;
  __shared__ int cnt;
  if (threadIdx.x == 0) cnt = 0;
  __syncthreads();
  int S = T.n[i]; if (S > 8192) S = 8192;
  const u16* p = (const u16*)T.p[i];
  int c = 0;
  for (int w = threadIdx.x; w < S; w += 256){
    u32 e = ((u32)p[w] >> 7) & 0xFFu;
    c += (e != 0u && (e < 96u || e > 159u)) ? 1 : 0;
  }
  atomicAdd(&cnt, c);
  __syncthreads();
  if (threadIdx.x == 0) fl[i] = (cnt > (S >> 4)) ? 0 : 1;
}

// ---- golden kernel: block = RR batch rows, plain layouts, F32 OUTPUT ----
__global__ __launch_bounds__(TPB) void actor_golden(PtrTab T, const int* flg, float* out, int Btot){
  __shared__ float A [RR][13][128];   // x (gn1 input); later h2 in cols 0..63
  __shared__ float Bf[RR][13][128];   // node-MLP hidden; later h1; later a2
  __shared__ u16   Cq[3][RR][13][64]; // k,q,v bf16; later a1 (as f32)
  __shared__ float obs_s[RR][111];
  __shared__ int   fls[NIN];

  const int tid = threadIdx.x;
  const int b0  = blockIdx.x * RR;

  if (tid < NIN){ int j = (tid >= 3 && (tid & 1)) ? tid - 1 : tid; fls[tid] = flg[j]; }
  __syncthreads();

  const bool BFobs = fls[0] != 0, BFlat = fls[1] != 0;

  // stage obs (clamp tail rows)
  for (int u = tid; u < RR * 111; u += TPB){
    int r = u / 111, c = u % 111;
    int br = b0 + r; if (br >= Btot) br = Btot - 1;
    obs_s[r][c] = ldv(T.p[0], br * 111 + c, BFobs);
  }
  __syncthreads();

  // Phase A: node-MLP hidden (elu) -> Bf[r][n][h]
  for (int u = tid; u < RR * 13 * 128; u += TPB){
    int r = u / 1664, rem = u % 1664, n = rem >> 7, h = rem & 127;
    int ty  = (n == 0) ? 0 : (n <= 4) ? 1 : (n <= 8) ? 2 : 3;
    int off = (n == 0) ? 0 : (ty == 1) ? 15 + 24 * (n - 1)
             : (ty == 2) ? 15 + 24 * (n - 5) + 8 : 15 + 24 * (n - 9) + 16;
    int K = (n == 0) ? 15 : 8;
    const void* w1 = T.p[2 + 4 * ty];
    bool bw = fls[2 + 4 * ty] != 0, bb = fls[3 + 4 * ty] != 0;
    float acc = ldv(T.p[3 + 4 * ty], h, bb);
    for (int k = 0; k < K; ++k) acc = fmaf(obs_s[r][off + k], ldv(w1, k * 128 + h, bw), acc);
    Bf[r][n][h] = eluf(acc);
  }
  __syncthreads();

  // Phase B: node-MLP out -> A[r][n][0..63]; latent -> A[r][n][64..127]
  for (int u = tid; u < 13 * 64; u += TPB){
    int n = u >> 6, o = u & 63;
    int ty = (n == 0) ? 0 : (n <= 4) ? 1 : (n <= 8) ? 2 : 3;
    const void* w2 = T.p[4 + 4 * ty];
    bool bw = fls[4 + 4 * ty] != 0, bb = fls[5 + 4 * ty] != 0;
    float b = ldv(T.p[5 + 4 * ty], o, bb);
    float acc[RR];
    #pragma unroll
    for (int r = 0; r < RR; ++r) acc[r] = b;
    for (int k = 0; k < 128; ++k){
      float w = ldv(w2, k * 64 + o, bw);
      #pragma unroll
      for (int r = 0; r < RR; ++r) acc[r] = fmaf(Bf[r][n][k], w, acc[r]);
    }
    #pragma unroll
    for (int r = 0; r < RR; ++r) A[r][n][o] = acc[r];
  }
  for (int u = tid; u < RR * 13 * 64; u += TPB){
    int r = u / 832, rem = u % 832, n = rem >> 6, j = rem & 63;
    int br = b0 + r; if (br >= Btot) br = Btot - 1;
    A[r][n][64 + j] = ldv(T.p[1], (br * 13 + n) * 64 + j, BFlat);
  }
  __syncthreads();

  // gn1 (output dim 128), two 64-column chunks
  for (int c0 = 0; c0 <= 64; c0 += 64){
    for (int u = tid; u < 3 * 832; u += TPB){
      int mat = u / 832, rem = u % 832, n = rem >> 6, j = rem & 63, col = c0 + j;
      const void* W = T.p[18 + 2 * mat];
      bool bw = fls[18 + 2 * mat] != 0, bb = fls[19 + 2 * mat] != 0;
      float b = ldv(T.p[19 + 2 * mat], col, bb);
      float acc[RR];
      #pragma unroll
      for (int r = 0; r < RR; ++r) acc[r] = b;
      for (int k = 0; k < 128; ++k){
        float w = ldv(W, k * 128 + col, bw);
        #pragma unroll
        for (int r = 0; r < RR; ++r) acc[r] = fmaf(A[r][n][k], w, acc[r]);
      }
      #pragma unroll
      for (int r = 0; r < RR; ++r) Cq[mat][r][n][j] = f2bf(acc[r]);
    }
    __syncthreads();
    for (int u = tid; u < 832; u += TPB){
      int n = u >> 6, j = u & 63, col = c0 + j;
      bool bw = fls[24] != 0, bb = fls[25] != 0;
      float b = ldv(T.p[25], col, bb);
      float acc[RR];
      #pragma unroll
      for (int r = 0; r < RR; ++r) acc[r] = b;
      for (int k = 0; k < 128; ++k){
        float w = ldv(T.p[24], k * 128 + col, bw);
        #pragma unroll
        for (int r = 0; r < RR; ++r) acc[r] = fmaf(A[r][n][k], w, acc[r]);
      }
      int cnt = nbr_cnt(n);
      for (int e = 0; e < cnt; ++e){
        int s = nbr_of(n, e);
        #pragma unroll
        for (int r = 0; r < RR; ++r){
          float g = sigmf(bf2f(Cq[0][r][n][j]) + bf2f(Cq[1][r][s][j]));
          acc[r] = fmaf(g, bf2f(Cq[2][r][s][j]), acc[r]);
        }
      }
      #pragma unroll
      for (int r = 0; r < RR; ++r) Bf[r][n][col] = eluf(acc[r]);
    }
    __syncthreads();
  }

  // gn2 (input h1 in Bf, output dim 64)
  for (int u = tid; u < 3 * 832; u += TPB){
    int mat = u / 832, rem = u % 832, n = rem >> 6, j = rem & 63;
    const void* W = T.p[26 + 2 * mat];
    bool bw = fls[26 + 2 * mat] != 0, bb = fls[27 + 2 * mat] != 0;
    float b = ldv(T.p[27 + 2 * mat], j, bb);
    float acc[RR];
    #pragma unroll
    for (int r = 0; r < RR; ++r) acc[r] = b;
    for (int k = 0; k < 128; ++k){
      float w = ldv(W, k * 64 + j, bw);
      #pragma unroll
      for (int r = 0; r < RR; ++r) acc[r] = fmaf(Bf[r][n][k], w, acc[r]);
    }
    #pragma unroll
    for (int r = 0; r < RR; ++r) Cq[mat][r][n][j] = f2bf(acc[r]);
  }
  __syncthreads();
  for (int u = tid; u < 832; u += TPB){
    int n = u >> 6, j = u & 63;
    bool bw = fls[32] != 0, bb = fls[33] != 0;
    float b = ldv(T.p[33], j, bb);
    float acc[RR];
    #pragma unroll
    for (int r = 0; r < RR; ++r) acc[r] = b;
    for (int k = 0; k < 128; ++k){
      float w = ldv(T.p[32], k * 64 + j, bw);
      #pragma unroll
      for (int r = 0; r < RR; ++r) acc[r] = fmaf(Bf[r][n][k], w, acc[r]);
    }
    int cnt = nbr_cnt(n);
    for (int e = 0; e < cnt; ++e){
      int s = nbr_of(n, e);
      #pragma unroll
      for (int r = 0; r < RR; ++r){
        float g = sigmf(bf2f(Cq[0][r][n][j]) + bf2f(Cq[1][r][s][j]));
        acc[r] = fmaf(g, bf2f(Cq[2][r][s][j]), acc[r]);
      }
    }
    #pragma unroll
    for (int r = 0; r < RR; ++r) A[r][n][j] = acc[r];   // h2 (no elu)
  }
  __syncthreads();

  // leg MLP: RR*4 instances. a1 reuses Cq as f32 [12][256]; a2 reuses Bf as [12][128].
  float* a1f = (float*)&Cq[0][0][0][0];
  float* a2f = (float*)&Bf[0][0][0];
  for (int u = tid; u < RR * 4 * 32; u += TPB){
    int inst = u >> 5, j0 = (u & 31) << 3;
    int r = inst >> 2, g = inst & 3;
    bool bw = fls[34] != 0, bb = fls[35] != 0;
    float acc8[8];
    #pragma unroll
    for (int jj = 0; jj < 8; ++jj) acc8[jj] = ldv(T.p[35], j0 + jj, bb);
    for (int k = 0; k < 256; ++k){
      float wf[8]; ld8(T.p[34], k * 256 + j0, bw, wf);
      int seg = k >> 6, f = k & 63;
      int node = (seg == 0) ? 0 : (seg - 1) * 4 + 1 + g;
      float xv = A[r][node][f];
      #pragma unroll
      for (int jj = 0; jj < 8; ++jj) acc8[jj] = fmaf(xv, wf[jj], acc8[jj]);
    }
    #pragma unroll
    for (int jj = 0; jj < 8; ++jj) a1f[inst * 256 + j0 + jj] = eluf(acc8[jj]);
  }
  __syncthreads();
  for (int u = tid; u < RR * 4 * 16; u += TPB){
    int inst = u >> 4, j0 = (u & 15) << 3;
    bool bw = fls[36] != 0, bb = fls[37] != 0;
    float acc8[8];
    #pragma unroll
    for (int jj = 0; jj < 8; ++jj) acc8[jj] = ldv(T.p[37], j0 + jj, bb);
    for (int k = 0; k < 256; ++k){
      float wf[8]; ld8(T.p[36], k * 128 + j0, bw, wf);
      float xv = a1f[inst * 256 + k];
      #pragma unroll
      for (int jj = 0; jj < 8; ++jj) acc8[jj] = fmaf(xv, wf[jj], acc8[jj]);
    }
    #pragma unroll
    for (int jj = 0; jj < 8; ++jj) a2f[inst * 128 + j0 + jj] = eluf(acc8[jj]);
  }
  __syncthreads();
  if (tid < RR * 4 * 3){
    int inst = tid / 3, c = tid % 3;
    int r = inst >> 2, g = inst & 3;
    bool bw = fls[38] != 0, bb = fls[39] != 0;
    float acc = ldv(T.p[39], c, bb);
    for (int k = 0; k < 128; ++k) acc = fmaf(a2f[inst * 128 + k], ldv(T.p[38], k * 3 + c, bw), acc);
    if (b0 + r < Btot) out[(b0 + r) * 12 + g * 3 + c] = acc;   // F32 output
  }
}

extern "C" void kernel_launch(void* const* d_in, const int* in_sizes, int n_in,
                              void* d_out, int out_size, void* d_ws, size_t ws_size,
                              hipStream_t stream){
  (void)out_size; (void)ws_size;
  PtrTab T;
  for (int i = 0; i < NIN; ++i){
    T.p[i] = (i < n_in) ? d_in[i] : d_in[0];
    T.n[i] = (i < n_in) ? in_sizes[i] : 1;
  }
  int* fl = (int*)d_ws;
  hipLaunchKernelGGL(probe_kernel, dim3(NIN), dim3(256), 0, stream, T, fl);

  int Btot = T.n[0] / 111;
  hipLaunchKernelGGL(actor_golden, dim3((unsigned)((Btot + RR - 1) / RR)), dim3(TPB), 0, stream,
                     T, fl, (float*)d_out, Btot);
}

// Round 7
// 2160.924 us; speedup vs baseline: 1.4599x; 1.4599x over previous
//
#include <hip/hip_runtime.h>

typedef unsigned short u16;
typedef unsigned int   u32;

#define TPB 512
#define RR  6
#define NIN 40

struct PtrTab { const void* p[NIN]; int n[NIN]; };

__device__ __forceinline__ float bf2f(u16 u){ union{u32 i; float f;} z; z.i = ((u32)u) << 16; return z.f; }
__device__ __forceinline__ u16 f2bf(float f){ union{float f; u32 i;} z; z.f = f; u32 u = z.i; return (u16)((u + 0x7fffu + ((u >> 16) & 1u)) >> 16); }
__device__ __forceinline__ float eluf(float x){ return x > 0.f ? x : (__expf(x) - 1.f); }
__device__ __forceinline__ float sigmf(float x){ return 1.f / (1.f + __expf(-x)); }

__device__ __forceinline__ float ldv(const void* p, int i, bool BF){
  if (BF){ return bf2f(((const u16*)p)[i]); }
  return ((const float*)p)[i];
}
// 8 consecutive bf16 from LDS/global (16B aligned)
__device__ __forceinline__ void bf8(const u16* p, float* f){
  uint4 w = *(const uint4*)(const void*)p;
  union{u32 i; float v;} t;
  t.i = w.x << 16; f[0] = t.v;  t.i = w.x & 0xffff0000u; f[1] = t.v;
  t.i = w.y << 16; f[2] = t.v;  t.i = w.y & 0xffff0000u; f[3] = t.v;
  t.i = w.z << 16; f[4] = t.v;  t.i = w.z & 0xffff0000u; f[5] = t.v;
  t.i = w.w << 16; f[6] = t.v;  t.i = w.w & 0xffff0000u; f[7] = t.v;
}
// dtype-generic 8-wide load; i multiple of 8
__device__ __forceinline__ void ld8(const void* p, int i, bool BF, float* f){
  if (BF){ bf8((const u16*)p + i, f); }
  else {
    const float4* q = (const float4*)(const void*)((const float*)p + i);
    float4 a = q[0], b = q[1];
    f[0]=a.x; f[1]=a.y; f[2]=a.z; f[3]=a.w; f[4]=b.x; f[5]=b.y; f[6]=b.z; f[7]=b.w;
  }
}

__device__ __forceinline__ int nbr_cnt(int n){ return n == 0 ? 4 : (n <= 8 ? 2 : 1); }
__device__ __forceinline__ int nbr_of(int n, int e){
  if (n == 0) return 1 + e;
  if (n <= 4) return e == 0 ? 0 : n + 4;
  if (n <= 8) return e == 0 ? n - 4 : n + 4;
  return n - 4;
}

// ---- per-input dtype probe (verified R6): 1 = bf16, 0 = f32 ----
__global__ __launch_bounds__(256) void probe_kernel(PtrTab T, int* fl){
  const int i = blockIdx.x;
  __shared__ int cnt;
  if (threadIdx.x == 0) cnt = 0;
  __syncthreads();
  int S = T.n[i]; if (S > 8192) S = 8192;
  const u16* p = (const u16*)T.p[i];
  int c = 0;
  for (int w = threadIdx.x; w < S; w += 256){
    u32 e = ((u32)p[w] >> 7) & 0xFFu;
    c += (e != 0u && (e < 96u || e > 159u)) ? 1 : 0;
  }
  atomicAdd(&cnt, c);
  __syncthreads();
  if (threadIdx.x == 0) fl[i] = (cnt > (S >> 4)) ? 0 : 1;
}

// ---- v2: RR=6 rows/block, 8-wide register tiles, padded LDS (stride 132) ----
__global__ __launch_bounds__(TPB) void actor_v2(PtrTab T, const int* flg, float* out, int Btot){
  __shared__ float A [RR][13][132];   // x; later h2 in cols 0..63            41184B
  __shared__ float Bf[RR][13][132];   // node hidden; s1; h1; later a2        41184B
  __shared__ u16   Cq[3][RR][13][128];// k,q,v bf16; later a1 (f32 overlay)   59904B
  __shared__ float obs_s[RR][111];    //                                       2664B
  __shared__ int   fls[NIN];

  const int tid = threadIdx.x;
  const int b0  = blockIdx.x * RR;

  if (tid < NIN){ int j = (tid >= 3 && (tid & 1)) ? tid - 1 : tid; fls[tid] = flg[j]; }
  __syncthreads();
  const bool BFobs = fls[0] != 0, BFlat = fls[1] != 0;

  // stage obs (clamp tail rows)
  for (int u = tid; u < RR * 111; u += TPB){
    int r = u / 111, c = u % 111;
    int br = b0 + r; if (br >= Btot) br = Btot - 1;
    obs_s[r][c] = ldv(T.p[0], br * 111 + c, BFobs);
  }
  __syncthreads();

  // Phase A: node-MLP hidden (elu) -> Bf[r][n][h]; items (r,n,h-group8)
  for (int u = tid; u < RR * 13 * 16; u += TPB){
    int r = u / 208, rem = u % 208, n = rem >> 4, h0 = (rem & 15) << 3;
    int ty  = (n == 0) ? 0 : (n <= 4) ? 1 : (n <= 8) ? 2 : 3;
    int off = (n == 0) ? 0 : (ty == 1) ? 15 + 24 * (n - 1)
             : (ty == 2) ? 15 + 24 * (n - 5) + 8 : 15 + 24 * (n - 9) + 16;
    int K = (n == 0) ? 15 : 8;
    const void* w1 = T.p[2 + 4 * ty];
    bool bw = fls[2 + 4 * ty] != 0, bb = fls[3 + 4 * ty] != 0;
    float acc8[8]; ld8(T.p[3 + 4 * ty], h0, bb, acc8);
    for (int k = 0; k < K; ++k){
      float xv = obs_s[r][off + k];
      float wf[8]; ld8(w1, k * 128 + h0, bw, wf);
      #pragma unroll
      for (int jj = 0; jj < 8; ++jj) acc8[jj] = fmaf(xv, wf[jj], acc8[jj]);
    }
    #pragma unroll
    for (int jj = 0; jj < 8; ++jj) Bf[r][n][h0 + jj] = eluf(acc8[jj]);
  }
  __syncthreads();

  // Phase B: node out -> A[.][.][0..63]; latent -> A[.][.][64..127]
  for (int u = tid; u < 13 * 8; u += TPB){   // (n, o-group8), acc[RR][8]
    int n = u >> 3, o0 = (u & 7) << 3;
    int ty = (n == 0) ? 0 : (n <= 4) ? 1 : (n <= 8) ? 2 : 3;
    const void* w2 = T.p[4 + 4 * ty];
    bool bw = fls[4 + 4 * ty] != 0, bb = fls[5 + 4 * ty] != 0;
    float bv[8]; ld8(T.p[5 + 4 * ty], o0, bb, bv);
    float acc[RR][8];
    #pragma unroll
    for (int r = 0; r < RR; ++r)
      #pragma unroll
      for (int jj = 0; jj < 8; ++jj) acc[r][jj] = bv[jj];
    #pragma unroll 4
    for (int k = 0; k < 128; ++k){
      float wf[8]; ld8(w2, k * 64 + o0, bw, wf);
      #pragma unroll
      for (int r = 0; r < RR; ++r){
        float xv = Bf[r][n][k];
        #pragma unroll
        for (int jj = 0; jj < 8; ++jj) acc[r][jj] = fmaf(xv, wf[jj], acc[r][jj]);
      }
    }
    #pragma unroll
    for (int r = 0; r < RR; ++r)
      #pragma unroll
      for (int jj = 0; jj < 8; ++jj) A[r][n][o0 + jj] = acc[r][jj];
  }
  for (int u = tid; u < RR * 13 * 8; u += TPB){   // latent, 8-wide
    int r = u / 104, rem = u % 104, n = rem >> 3, j0 = (rem & 7) << 3;
    int br = b0 + r; if (br >= Btot) br = Btot - 1;
    float lv[8]; ld8(T.p[1], (br * 13 + n) * 64 + j0, BFlat, lv);
    #pragma unroll
    for (int jj = 0; jj < 8; ++jj) A[r][n][64 + j0 + jj] = lv[jj];
  }
  __syncthreads();

  // gn1a: k,q,v -> Cq (bf16); s(+bias) -> Bf (f32). items (mat, n, j-group8 of 128)
  for (int u = tid; u < 4 * 13 * 16; u += TPB){
    int mat = u / 208, rem = u % 208, n = rem >> 4, j0 = (rem & 15) << 3;
    const void* W = T.p[18 + 2 * mat];
    bool bw = fls[18 + 2 * mat] != 0, bb = fls[19 + 2 * mat] != 0;
    float bv[8]; ld8(T.p[19 + 2 * mat], j0, bb, bv);
    float acc[RR][8];
    #pragma unroll
    for (int r = 0; r < RR; ++r)
      #pragma unroll
      for (int jj = 0; jj < 8; ++jj) acc[r][jj] = bv[jj];
    #pragma unroll 4
    for (int k = 0; k < 128; ++k){
      float wf[8]; ld8(W, k * 128 + j0, bw, wf);
      #pragma unroll
      for (int r = 0; r < RR; ++r){
        float xv = A[r][n][k];
        #pragma unroll
        for (int jj = 0; jj < 8; ++jj) acc[r][jj] = fmaf(xv, wf[jj], acc[r][jj]);
      }
    }
    if (mat < 3){
      #pragma unroll
      for (int r = 0; r < RR; ++r){
        u16 tmp[8];
        #pragma unroll
        for (int jj = 0; jj < 8; ++jj) tmp[jj] = f2bf(acc[r][jj]);
        *(uint4*)(void*)&Cq[mat][r][n][j0] = *(const uint4*)(const void*)tmp;
      }
    } else {
      #pragma unroll
      for (int r = 0; r < RR; ++r)
        #pragma unroll
        for (int jj = 0; jj < 8; ++jj) Bf[r][n][j0 + jj] = acc[r][jj];
    }
  }
  __syncthreads();

  // gn1b: gated aggregation + elu, in-place on Bf. items (r, n, j-group8)
  for (int u = tid; u < RR * 13 * 16; u += TPB){
    int r = u / 208, rem = u % 208, n = rem >> 4, j0 = (rem & 15) << 3;
    float acc8[8];
    #pragma unroll
    for (int jj = 0; jj < 8; ++jj) acc8[jj] = Bf[r][n][j0 + jj];
    float k8[8]; bf8(&Cq[0][r][n][j0], k8);
    int cnt = nbr_cnt(n);
    for (int e = 0; e < cnt; ++e){
      int s = nbr_of(n, e);
      float q8[8], v8[8];
      bf8(&Cq[1][r][s][j0], q8);
      bf8(&Cq[2][r][s][j0], v8);
      #pragma unroll
      for (int jj = 0; jj < 8; ++jj) acc8[jj] = fmaf(sigmf(k8[jj] + q8[jj]), v8[jj], acc8[jj]);
    }
    #pragma unroll
    for (int jj = 0; jj < 8; ++jj) Bf[r][n][j0 + jj] = eluf(acc8[jj]);
  }
  __syncthreads();

  // gn2a: k,q,v -> Cq; s(+bias) -> A (f32). out dim 64. items (mat, n, j-group8)
  for (int u = tid; u < 4 * 13 * 8; u += TPB){
    int mat = u / 104, rem = u % 104, n = rem >> 3, j0 = (rem & 7) << 3;
    const void* W = T.p[26 + 2 * mat];
    bool bw = fls[26 + 2 * mat] != 0, bb = fls[27 + 2 * mat] != 0;
    float bv[8]; ld8(T.p[27 + 2 * mat], j0, bb, bv);
    float acc[RR][8];
    #pragma unroll
    for (int r = 0; r < RR; ++r)
      #pragma unroll
      for (int jj = 0; jj < 8; ++jj) acc[r][jj] = bv[jj];
    #pragma unroll 4
    for (int k = 0; k < 128; ++k){
      float wf[8]; ld8(W, k * 64 + j0, bw, wf);
      #pragma unroll
      for (int r = 0; r < RR; ++r){
        float xv = Bf[r][n][k];
        #pragma unroll
        for (int jj = 0; jj < 8; ++jj) acc[r][jj] = fmaf(xv, wf[jj], acc[r][jj]);
      }
    }
    if (mat < 3){
      #pragma unroll
      for (int r = 0; r < RR; ++r){
        u16 tmp[8];
        #pragma unroll
        for (int jj = 0; jj < 8; ++jj) tmp[jj] = f2bf(acc[r][jj]);
        *(uint4*)(void*)&Cq[mat][r][n][j0] = *(const uint4*)(const void*)tmp;
      }
    } else {
      #pragma unroll
      for (int r = 0; r < RR; ++r)
        #pragma unroll
        for (int jj = 0; jj < 8; ++jj) A[r][n][j0 + jj] = acc[r][jj];
    }
  }
  __syncthreads();

  // gn2b: gated aggregation (no elu), in-place on A. items (r, n, j-group8)
  for (int u = tid; u < RR * 13 * 8; u += TPB){
    int r = u / 104, rem = u % 104, n = rem >> 3, j0 = (rem & 7) << 3;
    float acc8[8];
    #pragma unroll
    for (int jj = 0; jj < 8; ++jj) acc8[jj] = A[r][n][j0 + jj];
    float k8[8]; bf8(&Cq[0][r][n][j0], k8);
    int cnt = nbr_cnt(n);
    for (int e = 0; e < cnt; ++e){
      int s = nbr_of(n, e);
      float q8[8], v8[8];
      bf8(&Cq[1][r][s][j0], q8);
      bf8(&Cq[2][r][s][j0], v8);
      #pragma unroll
      for (int jj = 0; jj < 8; ++jj) acc8[jj] = fmaf(sigmf(k8[jj] + q8[jj]), v8[jj], acc8[jj]);
    }
    #pragma unroll
    for (int jj = 0; jj < 8; ++jj) A[r][n][j0 + jj] = acc8[jj];   // h2
  }
  __syncthreads();

  // leg MLP: 24 instances (r*4+g). a1 -> Cq overlay f32 [24][256]; a2 -> Bf overlay [24][128]
  float* a1f = (float*)&Cq[0][0][0][0];
  float* a2f = (float*)&Bf[0][0][0];
  { // a1: items (inst-quad, j-group8): 6*32 = 192, acc[4][8]
    bool bw = fls[34] != 0, bb = fls[35] != 0;
    for (int u = tid; u < 6 * 32; u += TPB){
      int iq = u >> 5, j0 = (u & 31) << 3;
      float bv[8]; ld8(T.p[35], j0, bb, bv);
      float acc[4][8];
      #pragma unroll
      for (int t = 0; t < 4; ++t)
        #pragma unroll
        for (int jj = 0; jj < 8; ++jj) acc[t][jj] = bv[jj];
      #pragma unroll 2
      for (int k = 0; k < 256; ++k){
        float wf[8]; ld8(T.p[34], k * 256 + j0, bw, wf);
        int seg = k >> 6, f = k & 63;
        #pragma unroll
        for (int t = 0; t < 4; ++t){
          int inst = iq * 4 + t, r = inst >> 2, g = inst & 3;
          int node = (seg == 0) ? 0 : (seg - 1) * 4 + 1 + g;
          float xv = A[r][node][f];
          #pragma unroll
          for (int jj = 0; jj < 8; ++jj) acc[t][jj] = fmaf(xv, wf[jj], acc[t][jj]);
        }
      }
      #pragma unroll
      for (int t = 0; t < 4; ++t){
        int inst = iq * 4 + t;
        #pragma unroll
        for (int jj = 0; jj < 8; ++jj) a1f[inst * 256 + j0 + jj] = eluf(acc[t][jj]);
      }
    }
  }
  __syncthreads();
  { // a2: items (inst-quad, j-group8): 6*16 = 96, acc[4][8]
    bool bw = fls[36] != 0, bb = fls[37] != 0;
    for (int u = tid; u < 6 * 16; u += TPB){
      int iq = u >> 4, j0 = (u & 15) << 3;
      float bv[8]; ld8(T.p[37], j0, bb, bv);
      float acc[4][8];
      #pragma unroll
      for (int t = 0; t < 4; ++t)
        #pragma unroll
        for (int jj = 0; jj < 8; ++jj) acc[t][jj] = bv[jj];
      #pragma unroll 2
      for (int k = 0; k < 256; ++k){
        float wf[8]; ld8(T.p[36], k * 128 + j0, bw, wf);
        #pragma unroll
        for (int t = 0; t < 4; ++t){
          float xv = a1f[(iq * 4 + t) * 256 + k];
          #pragma unroll
          for (int jj = 0; jj < 8; ++jj) acc[t][jj] = fmaf(xv, wf[jj], acc[t][jj]);
        }
      }
      #pragma unroll
      for (int t = 0; t < 4; ++t){
        int inst = iq * 4 + t;
        #pragma unroll
        for (int jj = 0; jj < 8; ++jj) a2f[inst * 128 + j0 + jj] = eluf(acc[t][jj]);
      }
    }
  }
  __syncthreads();
  if (tid < RR * 4 * 3){
    int inst = tid / 3, c = tid % 3;
    int r = inst >> 2, g = inst & 3;
    bool bw = fls[38] != 0, bb = fls[39] != 0;
    float acc = ldv(T.p[39], c, bb);
    for (int k = 0; k < 128; ++k) acc = fmaf(a2f[inst * 128 + k], ldv(T.p[38], k * 3 + c, bw), acc);
    if (b0 + r < Btot) out[(b0 + r) * 12 + g * 3 + c] = acc;
  }
}

extern "C" void kernel_launch(void* const* d_in, const int* in_sizes, int n_in,
                              void* d_out, int out_size, void* d_ws, size_t ws_size,
                              hipStream_t stream){
  (void)out_size; (void)ws_size;
  PtrTab T;
  for (int i = 0; i < NIN; ++i){
    T.p[i] = (i < n_in) ? d_in[i] : d_in[0];
    T.n[i] = (i < n_in) ? in_sizes[i] : 1;
  }
  int* fl = (int*)d_ws;
  hipLaunchKernelGGL(probe_kernel, dim3(NIN), dim3(256), 0, stream, T, fl);

  int Btot = T.n[0] / 111;
  hipLaunchKernelGGL(actor_v2, dim3((unsigned)((Btot + RR - 1) / RR)), dim3(TPB), 0, stream,
                     T, fl, (float*)d_out, Btot);
}

// Round 8
// 1203.054 us; speedup vs baseline: 2.6222x; 1.7962x over previous
//
#include <hip/hip_runtime.h>

typedef unsigned short u16;
typedef unsigned int   u32;

#define NIN 40

struct PtrTab { const void* p[NIN]; int n[NIN]; };
struct OffsT  { int o[38]; };   // bf16 element offsets of param slots 2..39 in ws

__device__ __forceinline__ float bf2f(u16 u){ union{u32 i; float f;} z; z.i = ((u32)u) << 16; return z.f; }
__device__ __forceinline__ u16 f2bf(float f){ union{float f; u32 i;} z; z.f = f; u32 u = z.i; return (u16)((u + 0x7fffu + ((u >> 16) & 1u)) >> 16); }
__device__ __forceinline__ float eluf(float x){ return x > 0.f ? x : (__expf(x) - 1.f); }
__device__ __forceinline__ float sigmf(float x){ return 1.f / (1.f + __expf(-x)); }

__device__ __forceinline__ float ldv(const void* p, int i, bool BF){
  if (BF){ return bf2f(((const u16*)p)[i]); }
  return ((const float*)p)[i];
}
// 8 consecutive bf16 (16B aligned) -> f32
__device__ __forceinline__ void bf8(const u16* p, float* f){
  uint4 w = *(const uint4*)(const void*)p;
  union{u32 i; float v;} t;
  t.i = w.x << 16; f[0] = t.v;  t.i = w.x & 0xffff0000u; f[1] = t.v;
  t.i = w.y << 16; f[2] = t.v;  t.i = w.y & 0xffff0000u; f[3] = t.v;
  t.i = w.z << 16; f[4] = t.v;  t.i = w.z & 0xffff0000u; f[5] = t.v;
  t.i = w.w << 16; f[6] = t.v;  t.i = w.w & 0xffff0000u; f[7] = t.v;
}
__device__ __forceinline__ void ld8(const void* p, int i, bool BF, float* f){
  if (BF){ bf8((const u16*)p + i, f); }
  else {
    const float4* q = (const float4*)(const void*)((const float*)p + i);
    float4 a = q[0], b = q[1];
    f[0]=a.x; f[1]=a.y; f[2]=a.z; f[3]=a.w; f[4]=b.x; f[5]=b.y; f[6]=b.z; f[7]=b.w;
  }
}
// store 8 f32 as bf16 (uint4)
__device__ __forceinline__ void st8bf(u16* p, const float* f){
  u16 tmp[8];
  #pragma unroll
  for (int jj = 0; jj < 8; ++jj) tmp[jj] = f2bf(f[jj]);
  *(uint4*)(void*)p = *(const uint4*)(const void*)tmp;
}

__device__ __forceinline__ int nbr_cnt(int n){ return n == 0 ? 4 : (n <= 8 ? 2 : 1); }
__device__ __forceinline__ int nbr_of(int n, int e){
  if (n == 0) return 1 + e;
  if (n <= 4) return e == 0 ? 0 : n + 4;
  if (n <= 8) return e == 0 ? n - 4 : n + 4;
  return n - 4;
}

// ---- per-input dtype probe (verified R6/R7): 1 = bf16, 0 = f32 ----
__global__ __launch_bounds__(256) void probe_kernel(PtrTab T, int* fl){
  const int i = blockIdx.x;
  __shared__ int cnt;
  if (threadIdx.x == 0) cnt = 0;
  __syncthreads();
  int S = T.n[i]; if (S > 8192) S = 8192;
  const u16* p = (const u16*)T.p[i];
  int c = 0;
  for (int w = threadIdx.x; w < S; w += 256){
    u32 e = ((u32)p[w] >> 7) & 0xFFu;
    c += (e != 0u && (e < 96u || e > 159u)) ? 1 : 0;
  }
  atomicAdd(&cnt, c);
  __syncthreads();
  if (threadIdx.x == 0) fl[i] = (cnt > (S >> 4)) ? 0 : 1;
}

// ---- convert all params (slots 2..39) to bf16 in ws ----
__global__ __launch_bounds__(256) void convert_kernel(PtrTab T, const int* fl, u16* dst, OffsT O){
  int s = blockIdx.x + 2;
  int j = (s >= 3 && (s & 1)) ? s - 1 : s;     // biases inherit weight's flag
  bool BF = fl[j] != 0;
  const void* src = T.p[s];
  u16* d = dst + O.o[s - 2];
  int n = T.n[s];
  for (int i = threadIdx.x; i < n; i += 256)
    d[i] = BF ? ((const u16*)src)[i] : f2bf(((const float*)src)[i]);
}

// ================= K1: node MLPs + gn1 + gn2 -> h2 (bf16, ws) =================
#define RR1 5
__global__ __launch_bounds__(512, 4) void k1(PtrTab T, const int* flg, const u16* W, OffsT O,
                                             u16* h2g, int Btot){
  __shared__ float obs_s[RR1][111];        //  2220 B
  __shared__ u16   A16[RR1][13][136];      // 17680 B  x (bf16)
  __shared__ u16   B16[RR1][13][136];      // 17680 B  hidden -> h1 (bf16)
  __shared__ u16   Cq[3][RR1][13][64];     // 24960 B  k,q,v (bf16, 64-col chunk)
  __shared__ float Sf[RR1][13][64];        // 16640 B  s (f32)

  const int tid = threadIdx.x;
  const int b0  = blockIdx.x * RR1;
  const bool BFobs = flg[0] != 0, BFlat = flg[1] != 0;

  // stage obs
  for (int u = tid; u < RR1 * 111; u += 512){
    int r = u / 111, c = u % 111;
    int br = b0 + r; if (br >= Btot) br = Btot - 1;
    obs_s[r][c] = ldv(T.p[0], br * 111 + c, BFobs);
  }
  __syncthreads();

  // Phase A: node-MLP hidden (elu) -> B16
  for (int u = tid; u < RR1 * 13 * 16; u += 512){
    int r = u / 208, rem = u % 208, n = rem >> 4, h0 = (rem & 15) << 3;
    int ty  = (n == 0) ? 0 : (n <= 4) ? 1 : (n <= 8) ? 2 : 3;
    int off = (n == 0) ? 0 : (ty == 1) ? 15 + 24 * (n - 1)
             : (ty == 2) ? 15 + 24 * (n - 5) + 8 : 15 + 24 * (n - 9) + 16;
    int K = (n == 0) ? 15 : 8;
    const u16* w1 = W + O.o[4 * ty];
    const u16* b1 = W + O.o[4 * ty + 1];
    float acc8[8]; bf8(b1 + h0, acc8);
    for (int k = 0; k < K; ++k){
      float xv = obs_s[r][off + k];
      float wf[8]; bf8(w1 + k * 128 + h0, wf);
      #pragma unroll
      for (int jj = 0; jj < 8; ++jj) acc8[jj] = fmaf(xv, wf[jj], acc8[jj]);
    }
    #pragma unroll
    for (int jj = 0; jj < 8; ++jj) acc8[jj] = eluf(acc8[jj]);
    st8bf(&B16[r][n][h0], acc8);
  }
  __syncthreads();

  // Phase B: node-MLP out -> A16 cols 0..63 ; latent -> A16 cols 64..127
  for (int u = tid; u < RR1 * 13 * 8; u += 512){
    int r = u / 104, rem = u % 104, n = rem >> 3, o0 = (rem & 7) << 3;
    int ty = (n == 0) ? 0 : (n <= 4) ? 1 : (n <= 8) ? 2 : 3;
    const u16* w2 = W + O.o[4 * ty + 2];
    const u16* b2 = W + O.o[4 * ty + 3];
    float acc8[8]; bf8(b2 + o0, acc8);
    #pragma unroll 4
    for (int k = 0; k < 128; ++k){
      float xv = bf2f(B16[r][n][k]);
      float wf[8]; bf8(w2 + k * 64 + o0, wf);
      #pragma unroll
      for (int jj = 0; jj < 8; ++jj) acc8[jj] = fmaf(xv, wf[jj], acc8[jj]);
    }
    st8bf(&A16[r][n][o0], acc8);
  }
  for (int u = tid; u < RR1 * 13 * 8; u += 512){
    int r = u / 104, rem = u % 104, n = rem >> 3, j0 = (rem & 7) << 3;
    int br = b0 + r; if (br >= Btot) br = Btot - 1;
    float lv[8]; ld8(T.p[1], (br * 13 + n) * 64 + j0, BFlat, lv);
    st8bf(&A16[r][n][64 + j0], lv);
  }
  __syncthreads();

  // gn1: two 64-col chunks
  for (int c0 = 0; c0 <= 64; c0 += 64){
    // kqvs: (mat, n, j-group8): 4*13*8 = 416 items, acc[RR1][8]
    for (int u = tid; u < 4 * 13 * 8; u += 512){
      int mat = u / 104, rem = u % 104, n = rem >> 3, j0 = (rem & 7) << 3, col = c0 + j0;
      const u16* Wm = W + O.o[16 + 2 * mat];
      const u16* Bm = W + O.o[17 + 2 * mat];
      float bv[8]; bf8(Bm + col, bv);
      float acc[RR1][8];
      #pragma unroll
      for (int r = 0; r < RR1; ++r)
        #pragma unroll
        for (int jj = 0; jj < 8; ++jj) acc[r][jj] = bv[jj];
      #pragma unroll 4
      for (int k = 0; k < 128; ++k){
        float wf[8]; bf8(Wm + k * 128 + col, wf);
        #pragma unroll
        for (int r = 0; r < RR1; ++r){
          float xv = bf2f(A16[r][n][k]);
          #pragma unroll
          for (int jj = 0; jj < 8; ++jj) acc[r][jj] = fmaf(xv, wf[jj], acc[r][jj]);
        }
      }
      if (mat < 3){
        #pragma unroll
        for (int r = 0; r < RR1; ++r) st8bf(&Cq[mat][r][n][j0], acc[r]);
      } else {
        #pragma unroll
        for (int r = 0; r < RR1; ++r)
          #pragma unroll
          for (int jj = 0; jj < 8; ++jj) Sf[r][n][j0 + jj] = acc[r][jj];
      }
    }
    __syncthreads();
    // gate + elu -> h1 (B16 cols c0..c0+63)
    for (int u = tid; u < RR1 * 13 * 8; u += 512){
      int r = u / 104, rem = u % 104, n = rem >> 3, j0 = (rem & 7) << 3;
      float acc8[8];
      #pragma unroll
      for (int jj = 0; jj < 8; ++jj) acc8[jj] = Sf[r][n][j0 + jj];
      float k8[8]; bf8(&Cq[0][r][n][j0], k8);
      int cnt = nbr_cnt(n);
      for (int e = 0; e < cnt; ++e){
        int s = nbr_of(n, e);
        float q8[8], v8[8];
        bf8(&Cq[1][r][s][j0], q8);
        bf8(&Cq[2][r][s][j0], v8);
        #pragma unroll
        for (int jj = 0; jj < 8; ++jj) acc8[jj] = fmaf(sigmf(k8[jj] + q8[jj]), v8[jj], acc8[jj]);
      }
      #pragma unroll
      for (int jj = 0; jj < 8; ++jj) acc8[jj] = eluf(acc8[jj]);
      st8bf(&B16[r][n][c0 + j0], acc8);
    }
    __syncthreads();
  }

  // gn2 (out dim 64, single pass): input h1 in B16
  for (int u = tid; u < 4 * 13 * 8; u += 512){
    int mat = u / 104, rem = u % 104, n = rem >> 3, j0 = (rem & 7) << 3;
    const u16* Wm = W + O.o[24 + 2 * mat];
    const u16* Bm = W + O.o[25 + 2 * mat];
    float bv[8]; bf8(Bm + j0, bv);
    float acc[RR1][8];
    #pragma unroll
    for (int r = 0; r < RR1; ++r)
      #pragma unroll
      for (int jj = 0; jj < 8; ++jj) acc[r][jj] = bv[jj];
    #pragma unroll 4
    for (int k = 0; k < 128; ++k){
      float wf[8]; bf8(Wm + k * 64 + j0, wf);
      #pragma unroll
      for (int r = 0; r < RR1; ++r){
        float xv = bf2f(B16[r][n][k]);
        #pragma unroll
        for (int jj = 0; jj < 8; ++jj) acc[r][jj] = fmaf(xv, wf[jj], acc[r][jj]);
      }
    }
    if (mat < 3){
      #pragma unroll
      for (int r = 0; r < RR1; ++r) st8bf(&Cq[mat][r][n][j0], acc[r]);
    } else {
      #pragma unroll
      for (int r = 0; r < RR1; ++r)
        #pragma unroll
        for (int jj = 0; jj < 8; ++jj) Sf[r][n][j0 + jj] = acc[r][jj];
    }
  }
  __syncthreads();
  // gate (no elu) -> h2 -> global ws (bf16)
  for (int u = tid; u < RR1 * 13 * 8; u += 512){
    int r = u / 104, rem = u % 104, n = rem >> 3, j0 = (rem & 7) << 3;
    float acc8[8];
    #pragma unroll
    for (int jj = 0; jj < 8; ++jj) acc8[jj] = Sf[r][n][j0 + jj];
    float k8[8]; bf8(&Cq[0][r][n][j0], k8);
    int cnt = nbr_cnt(n);
    for (int e = 0; e < cnt; ++e){
      int s = nbr_of(n, e);
      float q8[8], v8[8];
      bf8(&Cq[1][r][s][j0], q8);
      bf8(&Cq[2][r][s][j0], v8);
      #pragma unroll
      for (int jj = 0; jj < 8; ++jj) acc8[jj] = fmaf(sigmf(k8[jj] + q8[jj]), v8[jj], acc8[jj]);
    }
    if (b0 + r < Btot) st8bf(&h2g[((b0 + r) * 13 + n) * 64 + j0], acc8);
  }
}

// ================= K2: leg MLP from h2 (ws) -> out (f32) =================
#define K2I 48   // 12 rows x 4 legs per block
__global__ __launch_bounds__(512, 4) void k2(const u16* W, OffsT O, const u16* h2g,
                                             float* out, int Btot){
  __shared__ u16   lat[K2I][256];   // 24576 B
  __shared__ u16   a1s[K2I][256];   // 24576 B
  __shared__ float a2s[K2I][128];   // 24576 B
  const int tid = threadIdx.x;
  const int r0  = blockIdx.x * 12;

  // stage leg inputs (gather h2 by LEGS): 48 insts x 32 8-wide chunks
  for (int u = tid; u < K2I * 32; u += 512){
    int i = u >> 5, j0 = (u & 31) << 3;
    int r = i >> 2, g = i & 3;
    int br = r0 + r; if (br >= Btot) br = Btot - 1;
    int seg = j0 >> 6, f = j0 & 63;
    int node = (seg == 0) ? 0 : (seg - 1) * 4 + 1 + g;
    *(uint4*)(void*)&lat[i][j0] = *(const uint4*)(const void*)&h2g[(br * 13 + node) * 64 + f];
  }
  __syncthreads();

  // a1 = elu(lat @ w1 + b1): (inst-quad, j-group8) = 12*32 = 384 items
  {
    const u16* w1 = W + O.o[32], *b1 = W + O.o[33];
    for (int u = tid; u < 12 * 32; u += 512){
      int iq = u >> 5, j0 = (u & 31) << 3;
      float bv[8]; bf8(b1 + j0, bv);
      float acc[4][8];
      #pragma unroll
      for (int t = 0; t < 4; ++t)
        #pragma unroll
        for (int jj = 0; jj < 8; ++jj) acc[t][jj] = bv[jj];
      #pragma unroll 2
      for (int k = 0; k < 256; ++k){
        float wf[8]; bf8(w1 + k * 256 + j0, wf);
        #pragma unroll
        for (int t = 0; t < 4; ++t){
          float xv = bf2f(lat[iq * 4 + t][k]);
          #pragma unroll
          for (int jj = 0; jj < 8; ++jj) acc[t][jj] = fmaf(xv, wf[jj], acc[t][jj]);
        }
      }
      #pragma unroll
      for (int t = 0; t < 4; ++t){
        #pragma unroll
        for (int jj = 0; jj < 8; ++jj) acc[t][jj] = eluf(acc[t][jj]);
        st8bf(&a1s[iq * 4 + t][j0], acc[t]);
      }
    }
  }
  __syncthreads();

  // a2 = elu(a1 @ w2 + b2): (inst-quad, j-group8) = 12*16 = 192 items
  {
    const u16* w2 = W + O.o[34], *b2 = W + O.o[35];
    for (int u = tid; u < 12 * 16; u += 512){
      int iq = u >> 4, j0 = (u & 15) << 3;
      float bv[8]; bf8(b2 + j0, bv);
      float acc[4][8];
      #pragma unroll
      for (int t = 0; t < 4; ++t)
        #pragma unroll
        for (int jj = 0; jj < 8; ++jj) acc[t][jj] = bv[jj];
      #pragma unroll 2
      for (int k = 0; k < 256; ++k){
        float wf[8]; bf8(w2 + k * 128 + j0, wf);
        #pragma unroll
        for (int t = 0; t < 4; ++t){
          float xv = bf2f(a1s[iq * 4 + t][k]);
          #pragma unroll
          for (int jj = 0; jj < 8; ++jj) acc[t][jj] = fmaf(xv, wf[jj], acc[t][jj]);
        }
      }
      #pragma unroll
      for (int t = 0; t < 4; ++t)
        #pragma unroll
        for (int jj = 0; jj < 8; ++jj) a2s[iq * 4 + t][j0 + jj] = eluf(acc[t][jj]);
    }
  }
  __syncthreads();

  // out = a2 @ w3 + b3
  if (tid < K2I * 3){
    const u16* w3 = W + O.o[36], *b3 = W + O.o[37];
    int inst = tid / 3, c = tid % 3;
    int r = inst >> 2, g = inst & 3;
    float acc = bf2f(b3[c]);
    for (int k = 0; k < 128; ++k) acc = fmaf(a2s[inst][k], bf2f(w3[k * 3 + c]), acc);
    if (r0 + r < Btot) out[(r0 + r) * 12 + g * 3 + c] = acc;
  }
}

// ================= fallback: R7 monolithic kernel (proven) =================
#define TPB 512
#define RR  6
__global__ __launch_bounds__(TPB) void actor_v2(PtrTab T, const int* flg, float* out, int Btot){
  __shared__ float A [RR][13][132];
  __shared__ float Bf[RR][13][132];
  __shared__ u16   Cq[3][RR][13][128];
  __shared__ float obs_s[RR][111];
  __shared__ int   fls[NIN];

  const int tid = threadIdx.x;
  const int b0  = blockIdx.x * RR;

  if (tid < NIN){ int j = (tid >= 3 && (tid & 1)) ? tid - 1 : tid; fls[tid] = flg[j]; }
  __syncthreads();
  const bool BFobs = fls[0] != 0, BFlat = fls[1] != 0;

  for (int u = tid; u < RR * 111; u += TPB){
    int r = u / 111, c = u % 111;
    int br = b0 + r; if (br >= Btot) br = Btot - 1;
    obs_s[r][c] = ldv(T.p[0], br * 111 + c, BFobs);
  }
  __syncthreads();

  for (int u = tid; u < RR * 13 * 16; u += TPB){
    int r = u / 208, rem = u % 208, n = rem >> 4, h0 = (rem & 15) << 3;
    int ty  = (n == 0) ? 0 : (n <= 4) ? 1 : (n <= 8) ? 2 : 3;
    int off = (n == 0) ? 0 : (ty == 1) ? 15 + 24 * (n - 1)
             : (ty == 2) ? 15 + 24 * (n - 5) + 8 : 15 + 24 * (n - 9) + 16;
    int K = (n == 0) ? 15 : 8;
    const void* w1 = T.p[2 + 4 * ty];
    bool bw = fls[2 + 4 * ty] != 0, bb = fls[3 + 4 * ty] != 0;
    float acc8[8]; ld8(T.p[3 + 4 * ty], h0, bb, acc8);
    for (int k = 0; k < K; ++k){
      float xv = obs_s[r][off + k];
      float wf[8]; ld8(w1, k * 128 + h0, bw, wf);
      #pragma unroll
      for (int jj = 0; jj < 8; ++jj) acc8[jj] = fmaf(xv, wf[jj], acc8[jj]);
    }
    #pragma unroll
    for (int jj = 0; jj < 8; ++jj) Bf[r][n][h0 + jj] = eluf(acc8[jj]);
  }
  __syncthreads();

  for (int u = tid; u < 13 * 8; u += TPB){
    int n = u >> 3, o0 = (u & 7) << 3;
    int ty = (n == 0) ? 0 : (n <= 4) ? 1 : (n <= 8) ? 2 : 3;
    const void* w2 = T.p[4 + 4 * ty];
    bool bw = fls[4 + 4 * ty] != 0, bb = fls[5 + 4 * ty] != 0;
    float bv[8]; ld8(T.p[5 + 4 * ty], o0, bb, bv);
    float acc[RR][8];
    #pragma unroll
    for (int r = 0; r < RR; ++r)
      #pragma unroll
      for (int jj = 0; jj < 8; ++jj) acc[r][jj] = bv[jj];
    #pragma unroll 4
    for (int k = 0; k < 128; ++k){
      float wf[8]; ld8(w2, k * 64 + o0, bw, wf);
      #pragma unroll
      for (int r = 0; r < RR; ++r){
        float xv = Bf[r][n][k];
        #pragma unroll
        for (int jj = 0; jj < 8; ++jj) acc[r][jj] = fmaf(xv, wf[jj], acc[r][jj]);
      }
    }
    #pragma unroll
    for (int r = 0; r < RR; ++r)
      #pragma unroll
      for (int jj = 0; jj < 8; ++jj) A[r][n][o0 + jj] = acc[r][jj];
  }
  for (int u = tid; u < RR * 13 * 8; u += TPB){
    int r = u / 104, rem = u % 104, n = rem >> 3, j0 = (rem & 7) << 3;
    int br = b0 + r; if (br >= Btot) br = Btot - 1;
    float lv[8]; ld8(T.p[1], (br * 13 + n) * 64 + j0, BFlat, lv);
    #pragma unroll
    for (int jj = 0; jj < 8; ++jj) A[r][n][64 + j0 + jj] = lv[jj];
  }
  __syncthreads();

  for (int u = tid; u < 4 * 13 * 16; u += TPB){
    int mat = u / 208, rem = u % 208, n = rem >> 4, j0 = (rem & 15) << 3;
    const void* W = T.p[18 + 2 * mat];
    bool bw = fls[18 + 2 * mat] != 0, bb = fls[19 + 2 * mat] != 0;
    float bv[8]; ld8(T.p[19 + 2 * mat], j0, bb, bv);
    float acc[RR][8];
    #pragma unroll
    for (int r = 0; r < RR; ++r)
      #pragma unroll
      for (int jj = 0; jj < 8; ++jj) acc[r][jj] = bv[jj];
    #pragma unroll 4
    for (int k = 0; k < 128; ++k){
      float wf[8]; ld8(W, k * 128 + j0, bw, wf);
      #pragma unroll
      for (int r = 0; r < RR; ++r){
        float xv = A[r][n][k];
        #pragma unroll
        for (int jj = 0; jj < 8; ++jj) acc[r][jj] = fmaf(xv, wf[jj], acc[r][jj]);
      }
    }
    if (mat < 3){
      #pragma unroll
      for (int r = 0; r < RR; ++r) st8bf(&Cq[mat][r][n][j0], acc[r]);
    } else {
      #pragma unroll
      for (int r = 0; r < RR; ++r)
        #pragma unroll
        for (int jj = 0; jj < 8; ++jj) Bf[r][n][j0 + jj] = acc[r][jj];
    }
  }
  __syncthreads();

  for (int u = tid; u < RR * 13 * 16; u += TPB){
    int r = u / 208, rem = u % 208, n = rem >> 4, j0 = (rem & 15) << 3;
    float acc8[8];
    #pragma unroll
    for (int jj = 0; jj < 8; ++jj) acc8[jj] = Bf[r][n][j0 + jj];
    float k8[8]; bf8(&Cq[0][r][n][j0], k8);
    int cnt = nbr_cnt(n);
    for (int e = 0; e < cnt; ++e){
      int s = nbr_of(n, e);
      float q8[8], v8[8];
      bf8(&Cq[1][r][s][j0], q8);
      bf8(&Cq[2][r][s][j0], v8);
      #pragma unroll
      for (int jj = 0; jj < 8; ++jj) acc8[jj] = fmaf(sigmf(k8[jj] + q8[jj]), v8[jj], acc8[jj]);
    }
    #pragma unroll
    for (int jj = 0; jj < 8; ++jj) Bf[r][n][j0 + jj] = eluf(acc8[jj]);
  }
  __syncthreads();

  for (int u = tid; u < 4 * 13 * 8; u += TPB){
    int mat = u / 104, rem = u % 104, n = rem >> 3, j0 = (rem & 7) << 3;
    const void* W = T.p[26 + 2 * mat];
    bool bw = fls[26 + 2 * mat] != 0, bb = fls[27 + 2 * mat] != 0;
    float bv[8]; ld8(T.p[27 + 2 * mat], j0, bb, bv);
    float acc[RR][8];
    #pragma unroll
    for (int r = 0; r < RR; ++r)
      #pragma unroll
      for (int jj = 0; jj < 8; ++jj) acc[r][jj] = bv[jj];
    #pragma unroll 4
    for (int k = 0; k < 128; ++k){
      float wf[8]; ld8(W, k * 64 + j0, bw, wf);
      #pragma unroll
      for (int r = 0; r < RR; ++r){
        float xv = Bf[r][n][k];
        #pragma unroll
        for (int jj = 0; jj < 8; ++jj) acc[r][jj] = fmaf(xv, wf[jj], acc[r][jj]);
      }
    }
    if (mat < 3){
      #pragma unroll
      for (int r = 0; r < RR; ++r) st8bf(&Cq[mat][r][n][j0], acc[r]);
    } else {
      #pragma unroll
      for (int r = 0; r < RR; ++r)
        #pragma unroll
        for (int jj = 0; jj < 8; ++jj) A[r][n][j0 + jj] = acc[r][jj];
    }
  }
  __syncthreads();

  for (int u = tid; u < RR * 13 * 8; u += TPB){
    int r = u / 104, rem = u % 104, n = rem >> 3, j0 = (rem & 7) << 3;
    float acc8[8];
    #pragma unroll
    for (int jj = 0; jj < 8; ++jj) acc8[jj] = A[r][n][j0 + jj];
    float k8[8]; bf8(&Cq[0][r][n][j0], k8);
    int cnt = nbr_cnt(n);
    for (int e = 0; e < cnt; ++e){
      int s = nbr_of(n, e);
      float q8[8], v8[8];
      bf8(&Cq[1][r][s][j0], q8);
      bf8(&Cq[2][r][s][j0], v8);
      #pragma unroll
      for (int jj = 0; jj < 8; ++jj) acc8[jj] = fmaf(sigmf(k8[jj] + q8[jj]), v8[jj], acc8[jj]);
    }
    #pragma unroll
    for (int jj = 0; jj < 8; ++jj) A[r][n][j0 + jj] = acc8[jj];
  }
  __syncthreads();

  float* a1f = (float*)&Cq[0][0][0][0];
  float* a2f = (float*)&Bf[0][0][0];
  {
    bool bw = fls[34] != 0, bb = fls[35] != 0;
    for (int u = tid; u < 6 * 32; u += TPB){
      int iq = u >> 5, j0 = (u & 31) << 3;
      float bv[8]; ld8(T.p[35], j0, bb, bv);
      float acc[4][8];
      #pragma unroll
      for (int t = 0; t < 4; ++t)
        #pragma unroll
        for (int jj = 0; jj < 8; ++jj) acc[t][jj] = bv[jj];
      #pragma unroll 2
      for (int k = 0; k < 256; ++k){
        float wf[8]; ld8(T.p[34], k * 256 + j0, bw, wf);
        int seg = k >> 6, f = k & 63;
        #pragma unroll
        for (int t = 0; t < 4; ++t){
          int inst = iq * 4 + t, r = inst >> 2, g = inst & 3;
          int node = (seg == 0) ? 0 : (seg - 1) * 4 + 1 + g;
          float xv = A[r][node][f];
          #pragma unroll
          for (int jj = 0; jj < 8; ++jj) acc[t][jj] = fmaf(xv, wf[jj], acc[t][jj]);
        }
      }
      #pragma unroll
      for (int t = 0; t < 4; ++t){
        int inst = iq * 4 + t;
        #pragma unroll
        for (int jj = 0; jj < 8; ++jj) a1f[inst * 256 + j0 + jj] = eluf(acc[t][jj]);
      }
    }
  }
  __syncthreads();
  {
    bool bw = fls[36] != 0, bb = fls[37] != 0;
    for (int u = tid; u < 6 * 16; u += TPB){
      int iq = u >> 4, j0 = (u & 15) << 3;
      float bv[8]; ld8(T.p[37], j0, bb, bv);
      float acc[4][8];
      #pragma unroll
      for (int t = 0; t < 4; ++t)
        #pragma unroll
        for (int jj = 0; jj < 8; ++jj) acc[t][jj] = bv[jj];
      #pragma unroll 2
      for (int k = 0; k < 256; ++k){
        float wf[8]; ld8(T.p[36], k * 128 + j0, bw, wf);
        #pragma unroll
        for (int t = 0; t < 4; ++t){
          float xv = a1f[(iq * 4 + t) * 256 + k];
          #pragma unroll
          for (int jj = 0; jj < 8; ++jj) acc[t][jj] = fmaf(xv, wf[jj], acc[t][jj]);
        }
      }
      #pragma unroll
      for (int t = 0; t < 4; ++t){
        int inst = iq * 4 + t;
        #pragma unroll
        for (int jj = 0; jj < 8; ++jj) a2f[inst * 128 + j0 + jj] = eluf(acc[t][jj]);
      }
    }
  }
  __syncthreads();
  if (tid < RR * 4 * 3){
    int inst = tid / 3, c = tid % 3;
    int r = inst >> 2, g = inst & 3;
    bool bw = fls[38] != 0, bb = fls[39] != 0;
    float acc = ldv(T.p[39], c, bb);
    for (int k = 0; k < 128; ++k) acc = fmaf(a2f[inst * 128 + k], ldv(T.p[38], k * 3 + c, bw), acc);
    if (b0 + r < Btot) out[(b0 + r) * 12 + g * 3 + c] = acc;
  }
}

extern "C" void kernel_launch(void* const* d_in, const int* in_sizes, int n_in,
                              void* d_out, int out_size, void* d_ws, size_t ws_size,
                              hipStream_t stream){
  (void)out_size;
  PtrTab T;
  for (int i = 0; i < NIN; ++i){
    T.p[i] = (i < n_in) ? d_in[i] : d_in[0];
    T.n[i] = (i < n_in) ? in_sizes[i] : 1;
  }
  int* fl = (int*)d_ws;
  hipLaunchKernelGGL(probe_kernel, dim3(NIN), dim3(256), 0, stream, T, fl);

  int Btot = T.n[0] / 111;

  // bf16 weight offsets (8-element aligned)
  OffsT O;
  size_t acc = 0;
  for (int s = 0; s < 38; ++s){
    O.o[s] = (int)acc;
    acc += ((size_t)T.n[s + 2] + 7) & ~(size_t)7;
  }
  size_t h2off = ((256 + acc * 2 + 511) / 512) * 512;
  size_t need  = h2off + (size_t)Btot * 832 * 2;

  if (ws_size >= need){
    u16* Wb  = (u16*)((char*)d_ws + 256);
    u16* h2g = (u16*)((char*)d_ws + h2off);
    hipLaunchKernelGGL(convert_kernel, dim3(38), dim3(256), 0, stream, T, fl, Wb, O);
    hipLaunchKernelGGL(k1, dim3((unsigned)((Btot + RR1 - 1) / RR1)), dim3(512), 0, stream,
                       T, fl, Wb, O, h2g, Btot);
    hipLaunchKernelGGL(k2, dim3((unsigned)((Btot + 11) / 12)), dim3(512), 0, stream,
                       Wb, O, h2g, (float*)d_out, Btot);
  } else {
    hipLaunchKernelGGL(actor_v2, dim3((unsigned)((Btot + RR - 1) / RR)), dim3(TPB), 0, stream,
                       T, fl, (float*)d_out, Btot);
  }
}

// Round 9
// 605.757 us; speedup vs baseline: 5.2078x; 1.9860x over previous
//
#include <hip/hip_runtime.h>

typedef unsigned short u16;
typedef unsigned int   u32;

#define NIN 40

struct PtrTab { const void* p[NIN]; int n[NIN]; };
struct OffsT  { int o[38]; };   // bf16 element offsets of param slots 2..39 in ws
struct TOffs  { int o[12]; };   // transposed-mat element offsets in Wt region

typedef __attribute__((ext_vector_type(8))) short bf16x8;
typedef __attribute__((ext_vector_type(4))) float f32x4;
#define MFMA16(a,b,c) __builtin_amdgcn_mfma_f32_16x16x32_bf16(a,b,c,0,0,0)

__device__ __forceinline__ float bf2f(u16 u){ union{u32 i; float f;} z; z.i = ((u32)u) << 16; return z.f; }
__device__ __forceinline__ u16 f2bf(float f){ union{float f; u32 i;} z; z.f = f; u32 u = z.i; return (u16)((u + 0x7fffu + ((u >> 16) & 1u)) >> 16); }
__device__ __forceinline__ float eluf(float x){ return x > 0.f ? x : (__expf(x) - 1.f); }
__device__ __forceinline__ float sigmf(float x){ return 1.f / (1.f + __expf(-x)); }

__device__ __forceinline__ float ldv(const void* p, int i, bool BF){
  if (BF){ return bf2f(((const u16*)p)[i]); }
  return ((const float*)p)[i];
}
__device__ __forceinline__ void bf8(const u16* p, float* f){
  uint4 w = *(const uint4*)(const void*)p;
  union{u32 i; float v;} t;
  t.i = w.x << 16; f[0] = t.v;  t.i = w.x & 0xffff0000u; f[1] = t.v;
  t.i = w.y << 16; f[2] = t.v;  t.i = w.y & 0xffff0000u; f[3] = t.v;
  t.i = w.z << 16; f[4] = t.v;  t.i = w.z & 0xffff0000u; f[5] = t.v;
  t.i = w.w << 16; f[6] = t.v;  t.i = w.w & 0xffff0000u; f[7] = t.v;
}
__device__ __forceinline__ void ld8(const void* p, int i, bool BF, float* f){
  if (BF){ bf8((const u16*)p + i, f); }
  else {
    const float4* q = (const float4*)(const void*)((const float*)p + i);
    float4 a = q[0], b = q[1];
    f[0]=a.x; f[1]=a.y; f[2]=a.z; f[3]=a.w; f[4]=b.x; f[5]=b.y; f[6]=b.z; f[7]=b.w;
  }
}
__device__ __forceinline__ void st8bf(u16* p, const float* f){
  u16 tmp[8];
  #pragma unroll
  for (int jj = 0; jj < 8; ++jj) tmp[jj] = f2bf(f[jj]);
  *(uint4*)(void*)p = *(const uint4*)(const void*)tmp;
}

// ---- swizzled LDS helpers (G4: byte ^= (row&7)<<4 breaks stride-256B conflicts) ----
__device__ __forceinline__ void st8_swz(u16* base, int row, int k0, const float* f){
  int byte = (row*256 + k0*2) ^ ((row & 7) << 4);
  u16 tmp[8];
  #pragma unroll
  for (int jj = 0; jj < 8; ++jj) tmp[jj] = f2bf(f[jj]);
  *(uint4*)((char*)base + byte) = *(const uint4*)(const void*)tmp;
}
__device__ __forceinline__ void st1_swz(u16* base, int row, int col, float v){
  int byte = (row*256 + col*2) ^ ((row & 7) << 4);
  *(u16*)((char*)base + byte) = f2bf(v);
}
__device__ __forceinline__ bf16x8 ldfrag(const u16* base, int row, int k0){
  int byte = (row*256 + k0*2) ^ ((row & 7) << 4);
  return *(const bf16x8*)((const char*)base + byte);
}

__device__ __forceinline__ int nbr_cnt(int n){ return n == 0 ? 4 : (n <= 8 ? 2 : 1); }
__device__ __forceinline__ int nbr_of(int n, int e){
  if (n == 0) return 1 + e;
  if (n <= 4) return e == 0 ? 0 : n + 4;
  if (n <= 8) return e == 0 ? n - 4 : n + 4;
  return n - 4;
}

// ---- per-input dtype probe (verified R6-R8): 1 = bf16, 0 = f32 ----
__global__ __launch_bounds__(256) void probe_kernel(PtrTab T, int* fl){
  const int i = blockIdx.x;
  __shared__ int cnt;
  if (threadIdx.x == 0) cnt = 0;
  __syncthreads();
  int S = T.n[i]; if (S > 8192) S = 8192;
  const u16* p = (const u16*)T.p[i];
  int c = 0;
  for (int w = threadIdx.x; w < S; w += 256){
    u32 e = ((u32)p[w] >> 7) & 0xFFu;
    c += (e != 0u && (e < 96u || e > 159u)) ? 1 : 0;
  }
  atomicAdd(&cnt, c);
  __syncthreads();
  if (threadIdx.x == 0) fl[i] = (cnt > (S >> 4)) ? 0 : 1;
}

// ---- convert all params (slots 2..39) to bf16 in ws ----
__global__ __launch_bounds__(256) void convert_kernel(PtrTab T, const int* fl, u16* dst, OffsT O){
  int s = blockIdx.x + 2;
  int j = (s >= 3 && (s & 1)) ? s - 1 : s;
  bool BF = fl[j] != 0;
  const void* src = T.p[s];
  u16* d = dst + O.o[s - 2];
  int n = T.n[s];
  for (int i = threadIdx.x; i < n; i += 256)
    d[i] = BF ? ((const u16*)src)[i] : f2bf(((const float*)src)[i]);
}

// ---- transpose the 12 MFMA-consumed weight mats: W[k][c] -> Wt[c][k] (K=128) ----
__global__ __launch_bounds__(256) void transpose_kernel(const u16* Wb, OffsT O, u16* Wt, TOffs TF){
  static const int srcI[12] = {2,6,10,14, 16,18,20,22, 24,26,28,30};
  int m = blockIdx.x;
  int N = (m >= 4 && m < 8) ? 128 : 64;
  const u16* src = Wb + O.o[srcI[m]];
  u16* dst = Wt + TF.o[m];
  int tot = 128 * N;
  for (int i = threadIdx.x; i < tot; i += 256){
    int k = i / N, c = i % N;
    dst[c * 128 + k] = src[i];
  }
}

// ========== K1-MFMA: node MLPs + gn1 + gn2 -> h2 (bf16, ws). 16 rows/block ==========
__global__ __launch_bounds__(512, 2) void k1m(PtrTab T, const int* flg, const u16* Wb, OffsT O,
                                              const u16* Wt, TOffs TF, u16* h2g, int Btot){
  __shared__ u16 hidB[13*16*128];   // 53248B swizzled [n][r][k]: hidden, then h1
  __shared__ u16 xs  [13*16*128];   // 53248B swizzled: x; later h2 (plain, cols 0..63)
  __shared__ u16 wl  [2*32*128];    // 16384B weight tiles (phase B uses full as [64][128])
  __shared__ u16 qv  [2*13*16*32];  // 26624B q,v chunk (plain); aliased: obs_s f32[16][111]
  float* obs_s = (float*)qv;

  const int tid  = threadIdx.x;
  const int lane = tid & 63;
  const int wid  = tid >> 6;
  const int b0   = blockIdx.x * 16;
  const bool BFobs = flg[0] != 0, BFlat = flg[1] != 0;
  const int lrow = lane & 15;   // A-row / B-col / D-col
  const int lkg  = lane >> 4;   // k-group; D rows = lkg*4+i

  // stage obs (f32, aliased over qv)
  for (int u = tid; u < 16*111; u += 512){
    int r = u / 111, c = u % 111;
    int br = b0 + r; if (br >= Btot) br = Btot - 1;
    obs_s[r*111 + c] = ldv(T.p[0], br*111 + c, BFobs);
  }
  __syncthreads();

  // phase A: hidden = elu(obs @ w1 + b1) -> hidB (VALU; K small)
  for (int u = tid; u < 16*13*16; u += 512){
    int r = u / 208, rem = u % 208, n = rem >> 4, h0 = (rem & 15) << 3;
    int ty  = (n == 0) ? 0 : (n <= 4) ? 1 : (n <= 8) ? 2 : 3;
    int off = (n == 0) ? 0 : (ty == 1) ? 15 + 24 * (n - 1)
             : (ty == 2) ? 15 + 24 * (n - 5) + 8 : 15 + 24 * (n - 9) + 16;
    int K = (n == 0) ? 15 : 8;
    const u16* w1 = Wb + O.o[4*ty];
    float acc8[8]; bf8(Wb + O.o[4*ty+1] + h0, acc8);
    for (int k = 0; k < K; ++k){
      float xv = obs_s[r*111 + off + k];
      float wf[8]; bf8(w1 + k*128 + h0, wf);
      #pragma unroll
      for (int jj = 0; jj < 8; ++jj) acc8[jj] = fmaf(xv, wf[jj], acc8[jj]);
    }
    #pragma unroll
    for (int jj = 0; jj < 8; ++jj) acc8[jj] = eluf(acc8[jj]);
    st8_swz(hidB + n*2048, r, h0, acc8);
  }
  __syncthreads();   // hidB ready; obs dead

  // latent -> xs cols 64..127 (swizzled)
  for (int u = tid; u < 16*13*8; u += 512){
    int r = u / 104, rem = u % 104, n = rem >> 3, j0 = (rem & 7) << 3;
    int br = b0 + r; if (br >= Btot) br = Btot - 1;
    float lv[8]; ld8(T.p[1], (br*13 + n)*64 + j0, BFlat, lv);
    st8_swz(xs + n*2048, r, 64 + j0, lv);
  }

  // phase B (MFMA): x[:,0:64] = hidden @ w2[type] + b2
  for (int ty = 0; ty < 4; ++ty){
    const u16* src = Wt + TF.o[ty];          // [64][128]
    for (int u = tid; u < 1024; u += 512){
      int c = u >> 4, kg = (u & 15) << 3;
      uint4 v = *(const uint4*)(src + c*128 + kg);
      *(uint4*)((char*)wl + ((c*256 + kg*2) ^ ((c&7)<<4))) = v;
    }
    __syncthreads();
    int nn = ty ? 4 : 1, nb = ty ? (ty*4 - 3) : 0;
    const u16* b2 = Wb + O.o[4*ty + 3];
    for (int t = wid; t < nn*4; t += 8){
      int n = nb + (t >> 2), cb = t & 3;
      const u16* xb = hidB + n*2048;
      f32x4 d = {0.f,0.f,0.f,0.f};
      #pragma unroll
      for (int kk = 0; kk < 4; ++kk){
        bf16x8 a = ldfrag(xb, lrow, kk*32 + lkg*8);
        bf16x8 b = ldfrag(wl, cb*16 + lrow, kk*32 + lkg*8);
        d = MFMA16(a, b, d);
      }
      int c2 = cb*16 + lrow;
      float bvx = bf2f(b2[c2]);
      #pragma unroll
      for (int i = 0; i < 4; ++i)
        st1_swz(xs + n*2048, lkg*4 + i, c2, d[i] + bvx);
    }
    __syncthreads();
  }

  // ---------------- gn1 (MFMA, 4 chunks of 32 cols) ----------------
  {
    const u16* wt0 = Wt + TF.o[4]; const u16* wt1 = Wt + TF.o[5];
    const u16* wt2 = Wt + TF.o[6]; const u16* wt3 = Wt + TF.o[7];
    const u16* bk = Wb + O.o[17]; const u16* bq = Wb + O.o[19];
    const u16* bv = Wb + O.o[21]; const u16* bs = Wb + O.o[23];
    for (int c0 = 0; c0 < 128; c0 += 32){
      { // stage mat0 -> wl half 0
        int c = tid >> 4, kg = (tid & 15) << 3;
        uint4 v = *(const uint4*)(wt0 + (c0 + c)*128 + kg);
        *(uint4*)((char*)wl + ((c*256 + kg*2) ^ ((c&7)<<4))) = v;
      }
      __syncthreads();
      f32x4 kacc[4], sacc[4];
      #pragma unroll
      for (int m = 0; m < 4; ++m){
        if (m < 3){
          const u16* nxt = (m == 0) ? wt1 : (m == 1) ? wt2 : wt3;
          int c = tid >> 4, kg = (tid & 15) << 3;
          uint4 v = *(const uint4*)(nxt + (c0 + c)*128 + kg);
          *(uint4*)((char*)wl + (((m+1)&1)*8192) + ((c*256 + kg*2) ^ ((c&7)<<4))) = v;
        }
        const u16* wlh = wl + (m&1)*4096;
        #pragma unroll
        for (int tix = 0; tix < 4; ++tix){
          int t = wid + tix*8;
          if (t < 26){
            int n = t >> 1, cb = t & 1;
            const u16* xb = xs + n*2048;
            f32x4 d = {0.f,0.f,0.f,0.f};
            #pragma unroll
            for (int kk = 0; kk < 4; ++kk){
              bf16x8 a = ldfrag(xb, lrow, kk*32 + lkg*8);
              bf16x8 b = ldfrag(wlh, cb*16 + lrow, kk*32 + lkg*8);
              d = MFMA16(a, b, d);
            }
            if (m == 0) kacc[tix] = d;
            else if (m == 3) sacc[tix] = d;
            else {
              int cl = cb*16 + lrow;
              #pragma unroll
              for (int i = 0; i < 4; ++i)
                qv[(m-1)*6656 + (n*16 + lkg*4 + i)*32 + cl] = f2bf(d[i]);
            }
          }
        }
        __syncthreads();
      }
      // gating + elu -> h1 (hidB, swizzled)
      #pragma unroll
      for (int tix = 0; tix < 4; ++tix){
        int t = wid + tix*8;
        if (t < 26){
          int n = t >> 1, cb = t & 1;
          int cl = cb*16 + lrow, c = c0 + cl;
          float bkq = bf2f(bk[c]) + bf2f(bq[c]);
          float bvv = bf2f(bv[c]);
          float bss = bf2f(bs[c]);
          int cnt = nbr_cnt(n);
          #pragma unroll
          for (int i = 0; i < 4; ++i){
            int row = lkg*4 + i;
            float acc = sacc[tix][i] + bss;
            float kk_ = kacc[tix][i] + bkq;
            for (int e = 0; e < cnt; ++e){
              int s = nbr_of(n, e);
              float ql = bf2f(qv[(s*16 + row)*32 + cl]);
              float vl = bf2f(qv[6656 + (s*16 + row)*32 + cl]);
              acc += sigmf(kk_ + ql) * (vl + bvv);
            }
            st1_swz(hidB + n*2048, row, c, eluf(acc));
          }
        }
      }
      __syncthreads();
    }
  }

  // ---------------- gn2 (MFMA, 2 chunks of 32 cols; A = h1 in hidB) ----------------
  {
    const u16* wt0 = Wt + TF.o[8];  const u16* wt1 = Wt + TF.o[9];
    const u16* wt2 = Wt + TF.o[10]; const u16* wt3 = Wt + TF.o[11];
    const u16* bk = Wb + O.o[25]; const u16* bq = Wb + O.o[27];
    const u16* bv = Wb + O.o[29]; const u16* bs = Wb + O.o[31];
    for (int c0 = 0; c0 < 64; c0 += 32){
      {
        int c = tid >> 4, kg = (tid & 15) << 3;
        uint4 v = *(const uint4*)(wt0 + (c0 + c)*128 + kg);
        *(uint4*)((char*)wl + ((c*256 + kg*2) ^ ((c&7)<<4))) = v;
      }
      __syncthreads();
      f32x4 kacc[4], sacc[4];
      #pragma unroll
      for (int m = 0; m < 4; ++m){
        if (m < 3){
          const u16* nxt = (m == 0) ? wt1 : (m == 1) ? wt2 : wt3;
          int c = tid >> 4, kg = (tid & 15) << 3;
          uint4 v = *(const uint4*)(nxt + (c0 + c)*128 + kg);
          *(uint4*)((char*)wl + (((m+1)&1)*8192) + ((c*256 + kg*2) ^ ((c&7)<<4))) = v;
        }
        const u16* wlh = wl + (m&1)*4096;
        #pragma unroll
        for (int tix = 0; tix < 4; ++tix){
          int t = wid + tix*8;
          if (t < 26){
            int n = t >> 1, cb = t & 1;
            const u16* xb = hidB + n*2048;
            f32x4 d = {0.f,0.f,0.f,0.f};
            #pragma unroll
            for (int kk = 0; kk < 4; ++kk){
              bf16x8 a = ldfrag(xb, lrow, kk*32 + lkg*8);
              bf16x8 b = ldfrag(wlh, cb*16 + lrow, kk*32 + lkg*8);
              d = MFMA16(a, b, d);
            }
            if (m == 0) kacc[tix] = d;
            else if (m == 3) sacc[tix] = d;
            else {
              int cl = cb*16 + lrow;
              #pragma unroll
              for (int i = 0; i < 4; ++i)
                qv[(m-1)*6656 + (n*16 + lkg*4 + i)*32 + cl] = f2bf(d[i]);
            }
          }
        }
        __syncthreads();
      }
      // gating (no elu) -> h2 into xs (plain layout, cols 0..63)
      #pragma unroll
      for (int tix = 0; tix < 4; ++tix){
        int t = wid + tix*8;
        if (t < 26){
          int n = t >> 1, cb = t & 1;
          int cl = cb*16 + lrow, c = c0 + cl;
          float bkq = bf2f(bk[c]) + bf2f(bq[c]);
          float bvv = bf2f(bv[c]);
          float bss = bf2f(bs[c]);
          int cnt = nbr_cnt(n);
          #pragma unroll
          for (int i = 0; i < 4; ++i){
            int row = lkg*4 + i;
            float acc = sacc[tix][i] + bss;
            float kk_ = kacc[tix][i] + bkq;
            for (int e = 0; e < cnt; ++e){
              int s = nbr_of(n, e);
              float ql = bf2f(qv[(s*16 + row)*32 + cl]);
              float vl = bf2f(qv[6656 + (s*16 + row)*32 + cl]);
              acc += sigmf(kk_ + ql) * (vl + bvv);
            }
            xs[(n*16 + row)*128 + c] = f2bf(acc);
          }
        }
      }
      __syncthreads();
    }
  }

  // h2 -> global (coalesced b128)
  for (int u = tid; u < 13*16*8; u += 512){
    int n = u >> 7, rem = u & 127, r = rem >> 3, j0 = (rem & 7) << 3;
    if (b0 + r < Btot)
      *(uint4*)(h2g + ((b0 + r)*13 + n)*64 + j0) = *(const uint4*)(xs + (n*16 + r)*128 + j0);
  }
}

// ================= K2: leg MLP from h2 (ws) -> out (f32). UNCHANGED from R8 =================
#define K2I 48
__global__ __launch_bounds__(512, 4) void k2(const u16* W, OffsT O, const u16* h2g,
                                             float* out, int Btot){
  __shared__ u16   lat[K2I][256];
  __shared__ u16   a1s[K2I][256];
  __shared__ float a2s[K2I][128];
  const int tid = threadIdx.x;
  const int r0  = blockIdx.x * 12;

  for (int u = tid; u < K2I * 32; u += 512){
    int i = u >> 5, j0 = (u & 31) << 3;
    int r = i >> 2, g = i & 3;
    int br = r0 + r; if (br >= Btot) br = Btot - 1;
    int seg = j0 >> 6, f = j0 & 63;
    int node = (seg == 0) ? 0 : (seg - 1) * 4 + 1 + g;
    *(uint4*)(void*)&lat[i][j0] = *(const uint4*)(const void*)&h2g[(br * 13 + node) * 64 + f];
  }
  __syncthreads();
  {
    const u16* w1 = W + O.o[32], *b1 = W + O.o[33];
    for (int u = tid; u < 12 * 32; u += 512){
      int iq = u >> 5, j0 = (u & 31) << 3;
      float bvv[8]; bf8(b1 + j0, bvv);
      float acc[4][8];
      #pragma unroll
      for (int t = 0; t < 4; ++t)
        #pragma unroll
        for (int jj = 0; jj < 8; ++jj) acc[t][jj] = bvv[jj];
      #pragma unroll 2
      for (int k = 0; k < 256; ++k){
        float wf[8]; bf8(w1 + k * 256 + j0, wf);
        #pragma unroll
        for (int t = 0; t < 4; ++t){
          float xv = bf2f(lat[iq * 4 + t][k]);
          #pragma unroll
          for (int jj = 0; jj < 8; ++jj) acc[t][jj] = fmaf(xv, wf[jj], acc[t][jj]);
        }
      }
      #pragma unroll
      for (int t = 0; t < 4; ++t){
        #pragma unroll
        for (int jj = 0; jj < 8; ++jj) acc[t][jj] = eluf(acc[t][jj]);
        st8bf(&a1s[iq * 4 + t][j0], acc[t]);
      }
    }
  }
  __syncthreads();
  {
    const u16* w2 = W + O.o[34], *b2 = W + O.o[35];
    for (int u = tid; u < 12 * 16; u += 512){
      int iq = u >> 4, j0 = (u & 15) << 3;
      float bvv[8]; bf8(b2 + j0, bvv);
      float acc[4][8];
      #pragma unroll
      for (int t = 0; t < 4; ++t)
        #pragma unroll
        for (int jj = 0; jj < 8; ++jj) acc[t][jj] = bvv[jj];
      #pragma unroll 2
      for (int k = 0; k < 256; ++k){
        float wf[8]; bf8(w2 + k * 128 + j0, wf);
        #pragma unroll
        for (int t = 0; t < 4; ++t){
          float xv = bf2f(a1s[iq * 4 + t][k]);
          #pragma unroll
          for (int jj = 0; jj < 8; ++jj) acc[t][jj] = fmaf(xv, wf[jj], acc[t][jj]);
        }
      }
      #pragma unroll
      for (int t = 0; t < 4; ++t)
        #pragma unroll
        for (int jj = 0; jj < 8; ++jj) a2s[iq * 4 + t][j0 + jj] = eluf(acc[t][jj]);
    }
  }
  __syncthreads();
  if (tid < K2I * 3){
    const u16* w3 = W + O.o[36], *b3 = W + O.o[37];
    int inst = tid / 3, c = tid % 3;
    int r = inst >> 2, g = inst & 3;
    float acc = bf2f(b3[c]);
    for (int k = 0; k < 128; ++k) acc = fmaf(a2s[inst][k], bf2f(w3[k * 3 + c]), acc);
    if (r0 + r < Btot) out[(r0 + r) * 12 + g * 3 + c] = acc;
  }
}

// ================= fallback: R7 monolithic kernel (proven) =================
#define TPB 512
#define RR  6
__global__ __launch_bounds__(TPB) void actor_v2(PtrTab T, const int* flg, float* out, int Btot){
  __shared__ float A [RR][13][132];
  __shared__ float Bf[RR][13][132];
  __shared__ u16   Cq[3][RR][13][128];
  __shared__ float obs_s[RR][111];
  __shared__ int   fls[NIN];

  const int tid = threadIdx.x;
  const int b0  = blockIdx.x * RR;

  if (tid < NIN){ int j = (tid >= 3 && (tid & 1)) ? tid - 1 : tid; fls[tid] = flg[j]; }
  __syncthreads();
  const bool BFobs = fls[0] != 0, BFlat = fls[1] != 0;

  for (int u = tid; u < RR * 111; u += TPB){
    int r = u / 111, c = u % 111;
    int br = b0 + r; if (br >= Btot) br = Btot - 1;
    obs_s[r][c] = ldv(T.p[0], br * 111 + c, BFobs);
  }
  __syncthreads();

  for (int u = tid; u < RR * 13 * 16; u += TPB){
    int r = u / 208, rem = u % 208, n = rem >> 4, h0 = (rem & 15) << 3;
    int ty  = (n == 0) ? 0 : (n <= 4) ? 1 : (n <= 8) ? 2 : 3;
    int off = (n == 0) ? 0 : (ty == 1) ? 15 + 24 * (n - 1)
             : (ty == 2) ? 15 + 24 * (n - 5) + 8 : 15 + 24 * (n - 9) + 16;
    int K = (n == 0) ? 15 : 8;
    const void* w1 = T.p[2 + 4 * ty];
    bool bw = fls[2 + 4 * ty] != 0, bb = fls[3 + 4 * ty] != 0;
    float acc8[8]; ld8(T.p[3 + 4 * ty], h0, bb, acc8);
    for (int k = 0; k < K; ++k){
      float xv = obs_s[r][off + k];
      float wf[8]; ld8(w1, k * 128 + h0, bw, wf);
      #pragma unroll
      for (int jj = 0; jj < 8; ++jj) acc8[jj] = fmaf(xv, wf[jj], acc8[jj]);
    }
    #pragma unroll
    for (int jj = 0; jj < 8; ++jj) Bf[r][n][h0 + jj] = eluf(acc8[jj]);
  }
  __syncthreads();

  for (int u = tid; u < 13 * 8; u += TPB){
    int n = u >> 3, o0 = (u & 7) << 3;
    int ty = (n == 0) ? 0 : (n <= 4) ? 1 : (n <= 8) ? 2 : 3;
    const void* w2 = T.p[4 + 4 * ty];
    bool bw = fls[4 + 4 * ty] != 0, bb = fls[5 + 4 * ty] != 0;
    float bv[8]; ld8(T.p[5 + 4 * ty], o0, bb, bv);
    float acc[RR][8];
    #pragma unroll
    for (int r = 0; r < RR; ++r)
      #pragma unroll
      for (int jj = 0; jj < 8; ++jj) acc[r][jj] = bv[jj];
    #pragma unroll 4
    for (int k = 0; k < 128; ++k){
      float wf[8]; ld8(w2, k * 64 + o0, bw, wf);
      #pragma unroll
      for (int r = 0; r < RR; ++r){
        float xv = Bf[r][n][k];
        #pragma unroll
        for (int jj = 0; jj < 8; ++jj) acc[r][jj] = fmaf(xv, wf[jj], acc[r][jj]);
      }
    }
    #pragma unroll
    for (int r = 0; r < RR; ++r)
      #pragma unroll
      for (int jj = 0; jj < 8; ++jj) A[r][n][o0 + jj] = acc[r][jj];
  }
  for (int u = tid; u < RR * 13 * 8; u += TPB){
    int r = u / 104, rem = u % 104, n = rem >> 3, j0 = (rem & 7) << 3;
    int br = b0 + r; if (br >= Btot) br = Btot - 1;
    float lv[8]; ld8(T.p[1], (br * 13 + n) * 64 + j0, BFlat, lv);
    #pragma unroll
    for (int jj = 0; jj < 8; ++jj) A[r][n][64 + j0 + jj] = lv[jj];
  }
  __syncthreads();

  for (int u = tid; u < 4 * 13 * 16; u += TPB){
    int mat = u / 208, rem = u % 208, n = rem >> 4, j0 = (rem & 15) << 3;
    const void* W = T.p[18 + 2 * mat];
    bool bw = fls[18 + 2 * mat] != 0, bb = fls[19 + 2 * mat] != 0;
    float bv[8]; ld8(T.p[19 + 2 * mat], j0, bb, bv);
    float acc[RR][8];
    #pragma unroll
    for (int r = 0; r < RR; ++r)
      #pragma unroll
      for (int jj = 0; jj < 8; ++jj) acc[r][jj] = bv[jj];
    #pragma unroll 4
    for (int k = 0; k < 128; ++k){
      float wf[8]; ld8(W, k * 128 + j0, bw, wf);
      #pragma unroll
      for (int r = 0; r < RR; ++r){
        float xv = A[r][n][k];
        #pragma unroll
        for (int jj = 0; jj < 8; ++jj) acc[r][jj] = fmaf(xv, wf[jj], acc[r][jj]);
      }
    }
    if (mat < 3){
      #pragma unroll
      for (int r = 0; r < RR; ++r) st8bf(&Cq[mat][r][n][j0], acc[r]);
    } else {
      #pragma unroll
      for (int r = 0; r < RR; ++r)
        #pragma unroll
        for (int jj = 0; jj < 8; ++jj) Bf[r][n][j0 + jj] = acc[r][jj];
    }
  }
  __syncthreads();

  for (int u = tid; u < RR * 13 * 16; u += TPB){
    int r = u / 208, rem = u % 208, n = rem >> 4, j0 = (rem & 15) << 3;
    float acc8[8];
    #pragma unroll
    for (int jj = 0; jj < 8; ++jj) acc8[jj] = Bf[r][n][j0 + jj];
    float k8[8]; bf8(&Cq[0][r][n][j0], k8);
    int cnt = nbr_cnt(n);
    for (int e = 0; e < cnt; ++e){
      int s = nbr_of(n, e);
      float q8[8], v8[8];
      bf8(&Cq[1][r][s][j0], q8);
      bf8(&Cq[2][r][s][j0], v8);
      #pragma unroll
      for (int jj = 0; jj < 8; ++jj) acc8[jj] = fmaf(sigmf(k8[jj] + q8[jj]), v8[jj], acc8[jj]);
    }
    #pragma unroll
    for (int jj = 0; jj < 8; ++jj) Bf[r][n][j0 + jj] = eluf(acc8[jj]);
  }
  __syncthreads();

  for (int u = tid; u < 4 * 13 * 8; u += TPB){
    int mat = u / 104, rem = u % 104, n = rem >> 3, j0 = (rem & 7) << 3;
    const void* W = T.p[26 + 2 * mat];
    bool bw = fls[26 + 2 * mat] != 0, bb = fls[27 + 2 * mat] != 0;
    float bv[8]; ld8(T.p[27 + 2 * mat], j0, bb, bv);
    float acc[RR][8];
    #pragma unroll
    for (int r = 0; r < RR; ++r)
      #pragma unroll
      for (int jj = 0; jj < 8; ++jj) acc[r][jj] = bv[jj];
    #pragma unroll 4
    for (int k = 0; k < 128; ++k){
      float wf[8]; ld8(W, k * 64 + j0, bw, wf);
      #pragma unroll
      for (int r = 0; r < RR; ++r){
        float xv = Bf[r][n][k];
        #pragma unroll
        for (int jj = 0; jj < 8; ++jj) acc[r][jj] = fmaf(xv, wf[jj], acc[r][jj]);
      }
    }
    if (mat < 3){
      #pragma unroll
      for (int r = 0; r < RR; ++r) st8bf(&Cq[mat][r][n][j0], acc[r]);
    } else {
      #pragma unroll
      for (int r = 0; r < RR; ++r)
        #pragma unroll
        for (int jj = 0; jj < 8; ++jj) A[r][n][j0 + jj] = acc[r][jj];
    }
  }
  __syncthreads();

  for (int u = tid; u < RR * 13 * 8; u += TPB){
    int r = u / 104, rem = u % 104, n = rem >> 3, j0 = (rem & 7) << 3;
    float acc8[8];
    #pragma unroll
    for (int jj = 0; jj < 8; ++jj) acc8[jj] = A[r][n][j0 + jj];
    float k8[8]; bf8(&Cq[0][r][n][j0], k8);
    int cnt = nbr_cnt(n);
    for (int e = 0; e < cnt; ++e){
      int s = nbr_of(n, e);
      float q8[8], v8[8];
      bf8(&Cq[1][r][s][j0], q8);
      bf8(&Cq[2][r][s][j0], v8);
      #pragma unroll
      for (int jj = 0; jj < 8; ++jj) acc8[jj] = fmaf(sigmf(k8[jj] + q8[jj]), v8[jj], acc8[jj]);
    }
    #pragma unroll
    for (int jj = 0; jj < 8; ++jj) A[r][n][j0 + jj] = acc8[jj];
  }
  __syncthreads();

  float* a1f = (float*)&Cq[0][0][0][0];
  float* a2f = (float*)&Bf[0][0][0];
  {
    bool bw = fls[34] != 0, bb = fls[35] != 0;
    for (int u = tid; u < 6 * 32; u += TPB){
      int iq = u >> 5, j0 = (u & 31) << 3;
      float bv[8]; ld8(T.p[35], j0, bb, bv);
      float acc[4][8];
      #pragma unroll
      for (int t = 0; t < 4; ++t)
        #pragma unroll
        for (int jj = 0; jj < 8; ++jj) acc[t][jj] = bv[jj];
      #pragma unroll 2
      for (int k = 0; k < 256; ++k){
        float wf[8]; ld8(T.p[34], k * 256 + j0, bw, wf);
        int seg = k >> 6, f = k & 63;
        #pragma unroll
        for (int t = 0; t < 4; ++t){
          int inst = iq * 4 + t, r = inst >> 2, g = inst & 3;
          int node = (seg == 0) ? 0 : (seg - 1) * 4 + 1 + g;
          float xv = A[r][node][f];
          #pragma unroll
          for (int jj = 0; jj < 8; ++jj) acc[t][jj] = fmaf(xv, wf[jj], acc[t][jj]);
        }
      }
      #pragma unroll
      for (int t = 0; t < 4; ++t){
        int inst = iq * 4 + t;
        #pragma unroll
        for (int jj = 0; jj < 8; ++jj) a1f[inst * 256 + j0 + jj] = eluf(acc[t][jj]);
      }
    }
  }
  __syncthreads();
  {
    bool bw = fls[36] != 0, bb = fls[37] != 0;
    for (int u = tid; u < 6 * 16; u += TPB){
      int iq = u >> 4, j0 = (u & 15) << 3;
      float bv[8]; ld8(T.p[37], j0, bb, bv);
      float acc[4][8];
      #pragma unroll
      for (int t = 0; t < 4; ++t)
        #pragma unroll
        for (int jj = 0; jj < 8; ++jj) acc[t][jj] = bv[jj];
      #pragma unroll 2
      for (int k = 0; k < 256; ++k){
        float wf[8]; ld8(T.p[36], k * 128 + j0, bw, wf);
        #pragma unroll
        for (int t = 0; t < 4; ++t){
          float xv = a1f[(iq * 4 + t) * 256 + k];
          #pragma unroll
          for (int jj = 0; jj < 8; ++jj) acc[t][jj] = fmaf(xv, wf[jj], acc[t][jj]);
        }
      }
      #pragma unroll
      for (int t = 0; t < 4; ++t){
        int inst = iq * 4 + t;
        #pragma unroll
        for (int jj = 0; jj < 8; ++jj) a2f[inst * 128 + j0 + jj] = eluf(acc[t][jj]);
      }
    }
  }
  __syncthreads();
  if (tid < RR * 4 * 3){
    int inst = tid / 3, c = tid % 3;
    int r = inst >> 2, g = inst & 3;
    bool bw = fls[38] != 0, bb = fls[39] != 0;
    float acc = ldv(T.p[39], c, bb);
    for (int k = 0; k < 128; ++k) acc = fmaf(a2f[inst * 128 + k], ldv(T.p[38], k * 3 + c, bw), acc);
    if (b0 + r < Btot) out[(b0 + r) * 12 + g * 3 + c] = acc;
  }
}

extern "C" void kernel_launch(void* const* d_in, const int* in_sizes, int n_in,
                              void* d_out, int out_size, void* d_ws, size_t ws_size,
                              hipStream_t stream){
  (void)out_size;
  PtrTab T;
  for (int i = 0; i < NIN; ++i){
    T.p[i] = (i < n_in) ? d_in[i] : d_in[0];
    T.n[i] = (i < n_in) ? in_sizes[i] : 1;
  }
  int* fl = (int*)d_ws;
  hipLaunchKernelGGL(probe_kernel, dim3(NIN), dim3(256), 0, stream, T, fl);

  int Btot = T.n[0] / 111;

  OffsT O;
  size_t acc = 0;
  for (int s = 0; s < 38; ++s){
    O.o[s] = (int)acc;
    acc += ((size_t)T.n[s + 2] + 7) & ~(size_t)7;
  }
  TOffs TF;
  { int off = 0;
    for (int m = 0; m < 12; ++m){
      TF.o[m] = off;
      off += 128 * ((m >= 4 && m < 8) ? 128 : 64);
    }
  }
  size_t wtoff = ((256 + acc * 2 + 511) / 512) * 512;          // byte offset of Wt
  size_t h2off = ((wtoff + 131072 * 2 + 511) / 512) * 512;     // byte offset of h2g
  size_t need  = h2off + (size_t)Btot * 832 * 2;

  if (ws_size >= need){
    u16* Wb  = (u16*)((char*)d_ws + 256);
    u16* Wt  = (u16*)((char*)d_ws + wtoff);
    u16* h2g = (u16*)((char*)d_ws + h2off);
    hipLaunchKernelGGL(convert_kernel, dim3(38), dim3(256), 0, stream, T, fl, Wb, O);
    hipLaunchKernelGGL(transpose_kernel, dim3(12), dim3(256), 0, stream, Wb, O, Wt, TF);
    hipLaunchKernelGGL(k1m, dim3((unsigned)((Btot + 15) / 16)), dim3(512), 0, stream,
                       T, fl, Wb, O, Wt, TF, h2g, Btot);
    hipLaunchKernelGGL(k2, dim3((unsigned)((Btot + 11) / 12)), dim3(512), 0, stream,
                       Wb, O, h2g, (float*)d_out, Btot);
  } else {
    hipLaunchKernelGGL(actor_v2, dim3((unsigned)((Btot + RR - 1) / RR)), dim3(TPB), 0, stream,
                       T, fl, (float*)d_out, Btot);
  }
}

// Round 10
// 448.783 us; speedup vs baseline: 7.0294x; 1.3498x over previous
//
#include <hip/hip_runtime.h>

typedef unsigned short u16;
typedef unsigned int   u32;

#define NIN 40

struct PtrTab { const void* p[NIN]; int n[NIN]; };
struct OffsT  { int o[38]; };   // bf16 element offsets of param slots 2..39 in ws
struct TOffs  { int o[14]; };   // transposed-mat element offsets in Wt region

typedef __attribute__((ext_vector_type(8))) short bf16x8;
typedef __attribute__((ext_vector_type(4))) float f32x4;
#define MFMA16(a,b,c) __builtin_amdgcn_mfma_f32_16x16x32_bf16(a,b,c,0,0,0)

__device__ __forceinline__ float bf2f(u16 u){ union{u32 i; float f;} z; z.i = ((u32)u) << 16; return z.f; }
__device__ __forceinline__ u16 f2bf(float f){ union{float f; u32 i;} z; z.f = f; u32 u = z.i; return (u16)((u + 0x7fffu + ((u >> 16) & 1u)) >> 16); }
__device__ __forceinline__ float eluf(float x){ return x > 0.f ? x : (__expf(x) - 1.f); }
__device__ __forceinline__ float sigmf(float x){ return 1.f / (1.f + __expf(-x)); }

__device__ __forceinline__ float ldv(const void* p, int i, bool BF){
  if (BF){ return bf2f(((const u16*)p)[i]); }
  return ((const float*)p)[i];
}
__device__ __forceinline__ void bf8(const u16* p, float* f){
  uint4 w = *(const uint4*)(const void*)p;
  union{u32 i; float v;} t;
  t.i = w.x << 16; f[0] = t.v;  t.i = w.x & 0xffff0000u; f[1] = t.v;
  t.i = w.y << 16; f[2] = t.v;  t.i = w.y & 0xffff0000u; f[3] = t.v;
  t.i = w.z << 16; f[4] = t.v;  t.i = w.z & 0xffff0000u; f[5] = t.v;
  t.i = w.w << 16; f[6] = t.v;  t.i = w.w & 0xffff0000u; f[7] = t.v;
}
__device__ __forceinline__ void ld8(const void* p, int i, bool BF, float* f){
  if (BF){ bf8((const u16*)p + i, f); }
  else {
    const float4* q = (const float4*)(const void*)((const float*)p + i);
    float4 a = q[0], b = q[1];
    f[0]=a.x; f[1]=a.y; f[2]=a.z; f[3]=a.w; f[4]=b.x; f[5]=b.y; f[6]=b.z; f[7]=b.w;
  }
}
__device__ __forceinline__ void st8bf(u16* p, const float* f){
  u16 tmp[8];
  #pragma unroll
  for (int jj = 0; jj < 8; ++jj) tmp[jj] = f2bf(f[jj]);
  *(uint4*)(void*)p = *(const uint4*)(const void*)tmp;
}

// ---- swizzled LDS helpers (G4: byte ^= (row&7)<<4) ----
__device__ __forceinline__ void st8_swz(u16* base, int row, int k0, const float* f){
  int byte = (row*256 + k0*2) ^ ((row & 7) << 4);
  u16 tmp[8];
  #pragma unroll
  for (int jj = 0; jj < 8; ++jj) tmp[jj] = f2bf(f[jj]);
  *(uint4*)((char*)base + byte) = *(const uint4*)(const void*)tmp;
}
__device__ __forceinline__ void st1_swz(u16* base, int row, int col, float v){
  int byte = (row*256 + col*2) ^ ((row & 7) << 4);
  *(u16*)((char*)base + byte) = f2bf(v);
}
__device__ __forceinline__ bf16x8 ldfrag(const u16* base, int row, int k0){
  int byte = (row*256 + k0*2) ^ ((row & 7) << 4);
  return *(const bf16x8*)((const char*)base + byte);
}
// 512-byte-stride variants (K=256 tiles in k2m)
__device__ __forceinline__ bf16x8 ldfrag5(const u16* base, int row, int k0){
  int byte = (row*512 + k0*2) ^ ((row & 7) << 4);
  return *(const bf16x8*)((const char*)base + byte);
}
__device__ __forceinline__ void st1_5(u16* base, int row, int col, float v){
  int byte = (row*512 + col*2) ^ ((row & 7) << 4);
  *(u16*)((char*)base + byte) = f2bf(v);
}

__device__ __forceinline__ int nbr_cnt(int n){ return n == 0 ? 4 : (n <= 8 ? 2 : 1); }
__device__ __forceinline__ int nbr_of(int n, int e){
  if (n == 0) return 1 + e;
  if (n <= 4) return e == 0 ? 0 : n + 4;
  if (n <= 8) return e == 0 ? n - 4 : n + 4;
  return n - 4;
}

// ---- per-input dtype probe (verified R6-R9): 1 = bf16, 0 = f32 ----
__global__ __launch_bounds__(256) void probe_kernel(PtrTab T, int* fl){
  const int i = blockIdx.x;
  __shared__ int cnt;
  if (threadIdx.x == 0) cnt = 0;
  __syncthreads();
  int S = T.n[i]; if (S > 8192) S = 8192;
  const u16* p = (const u16*)T.p[i];
  int c = 0;
  for (int w = threadIdx.x; w < S; w += 256){
    u32 e = ((u32)p[w] >> 7) & 0xFFu;
    c += (e != 0u && (e < 96u || e > 159u)) ? 1 : 0;
  }
  atomicAdd(&cnt, c);
  __syncthreads();
  if (threadIdx.x == 0) fl[i] = (cnt > (S >> 4)) ? 0 : 1;
}

// ---- convert all params (slots 2..39) to bf16 in ws ----
__global__ __launch_bounds__(256) void convert_kernel(PtrTab T, const int* fl, u16* dst, OffsT O){
  int s = blockIdx.x + 2;
  int j = (s >= 3 && (s & 1)) ? s - 1 : s;
  bool BF = fl[j] != 0;
  const void* src = T.p[s];
  u16* d = dst + O.o[s - 2];
  int n = T.n[s];
  for (int i = threadIdx.x; i < n; i += 256)
    d[i] = BF ? ((const u16*)src)[i] : f2bf(((const float*)src)[i]);
}

// ---- transpose 14 MFMA-consumed weight mats: W[k][c] -> Wt[c][k] ----
__global__ __launch_bounds__(256) void transpose_kernel(const u16* Wb, OffsT O, u16* Wt, TOffs TF){
  static const int srcI[14] = {2,6,10,14, 16,18,20,22, 24,26,28,30, 32,34};
  static const int KK[14]   = {128,128,128,128, 128,128,128,128, 128,128,128,128, 256,256};
  static const int NNm[14]  = {64,64,64,64, 128,128,128,128, 64,64,64,64, 256,128};
  int m = blockIdx.x;
  int K = KK[m], N = NNm[m];
  const u16* src = Wb + O.o[srcI[m]];
  u16* dst = Wt + TF.o[m];
  int tot = K * N;
  for (int i = threadIdx.x; i < tot; i += 256){
    int k = i / N, c = i % N;
    dst[c * K + k] = src[i];
  }
}

// ========== K1-MFMA (UNCHANGED from R9): node MLPs + gn1 + gn2 -> h2 ==========
__global__ __launch_bounds__(512, 2) void k1m(PtrTab T, const int* flg, const u16* Wb, OffsT O,
                                              const u16* Wt, TOffs TF, u16* h2g, int Btot){
  __shared__ u16 hidB[13*16*128];
  __shared__ u16 xs  [13*16*128];
  __shared__ u16 wl  [2*32*128];
  __shared__ u16 qv  [2*13*16*32];
  float* obs_s = (float*)qv;

  const int tid  = threadIdx.x;
  const int lane = tid & 63;
  const int wid  = tid >> 6;
  const int b0   = blockIdx.x * 16;
  const bool BFobs = flg[0] != 0, BFlat = flg[1] != 0;
  const int lrow = lane & 15;
  const int lkg  = lane >> 4;

  for (int u = tid; u < 16*111; u += 512){
    int r = u / 111, c = u % 111;
    int br = b0 + r; if (br >= Btot) br = Btot - 1;
    obs_s[r*111 + c] = ldv(T.p[0], br*111 + c, BFobs);
  }
  __syncthreads();

  for (int u = tid; u < 16*13*16; u += 512){
    int r = u / 208, rem = u % 208, n = rem >> 4, h0 = (rem & 15) << 3;
    int ty  = (n == 0) ? 0 : (n <= 4) ? 1 : (n <= 8) ? 2 : 3;
    int off = (n == 0) ? 0 : (ty == 1) ? 15 + 24 * (n - 1)
             : (ty == 2) ? 15 + 24 * (n - 5) + 8 : 15 + 24 * (n - 9) + 16;
    int K = (n == 0) ? 15 : 8;
    const u16* w1 = Wb + O.o[4*ty];
    float acc8[8]; bf8(Wb + O.o[4*ty+1] + h0, acc8);
    for (int k = 0; k < K; ++k){
      float xv = obs_s[r*111 + off + k];
      float wf[8]; bf8(w1 + k*128 + h0, wf);
      #pragma unroll
      for (int jj = 0; jj < 8; ++jj) acc8[jj] = fmaf(xv, wf[jj], acc8[jj]);
    }
    #pragma unroll
    for (int jj = 0; jj < 8; ++jj) acc8[jj] = eluf(acc8[jj]);
    st8_swz(hidB + n*2048, r, h0, acc8);
  }
  __syncthreads();

  for (int u = tid; u < 16*13*8; u += 512){
    int r = u / 104, rem = u % 104, n = rem >> 3, j0 = (rem & 7) << 3;
    int br = b0 + r; if (br >= Btot) br = Btot - 1;
    float lv[8]; ld8(T.p[1], (br*13 + n)*64 + j0, BFlat, lv);
    st8_swz(xs + n*2048, r, 64 + j0, lv);
  }

  for (int ty = 0; ty < 4; ++ty){
    const u16* src = Wt + TF.o[ty];
    for (int u = tid; u < 1024; u += 512){
      int c = u >> 4, kg = (u & 15) << 3;
      uint4 v = *(const uint4*)(src + c*128 + kg);
      *(uint4*)((char*)wl + ((c*256 + kg*2) ^ ((c&7)<<4))) = v;
    }
    __syncthreads();
    int nn = ty ? 4 : 1, nb = ty ? (ty*4 - 3) : 0;
    const u16* b2 = Wb + O.o[4*ty + 3];
    for (int t = wid; t < nn*4; t += 8){
      int n = nb + (t >> 2), cb = t & 3;
      const u16* xb = hidB + n*2048;
      f32x4 d = {0.f,0.f,0.f,0.f};
      #pragma unroll
      for (int kk = 0; kk < 4; ++kk){
        bf16x8 a = ldfrag(xb, lrow, kk*32 + lkg*8);
        bf16x8 b = ldfrag(wl, cb*16 + lrow, kk*32 + lkg*8);
        d = MFMA16(a, b, d);
      }
      int c2 = cb*16 + lrow;
      float bvx = bf2f(b2[c2]);
      #pragma unroll
      for (int i = 0; i < 4; ++i)
        st1_swz(xs + n*2048, lkg*4 + i, c2, d[i] + bvx);
    }
    __syncthreads();
  }

  {
    const u16* wt0 = Wt + TF.o[4]; const u16* wt1 = Wt + TF.o[5];
    const u16* wt2 = Wt + TF.o[6]; const u16* wt3 = Wt + TF.o[7];
    const u16* bk = Wb + O.o[17]; const u16* bq = Wb + O.o[19];
    const u16* bv = Wb + O.o[21]; const u16* bs = Wb + O.o[23];
    for (int c0 = 0; c0 < 128; c0 += 32){
      {
        int c = tid >> 4, kg = (tid & 15) << 3;
        uint4 v = *(const uint4*)(wt0 + (c0 + c)*128 + kg);
        *(uint4*)((char*)wl + ((c*256 + kg*2) ^ ((c&7)<<4))) = v;
      }
      __syncthreads();
      f32x4 kacc[4], sacc[4];
      #pragma unroll
      for (int m = 0; m < 4; ++m){
        if (m < 3){
          const u16* nxt = (m == 0) ? wt1 : (m == 1) ? wt2 : wt3;
          int c = tid >> 4, kg = (tid & 15) << 3;
          uint4 v = *(const uint4*)(nxt + (c0 + c)*128 + kg);
          *(uint4*)((char*)wl + (((m+1)&1)*8192) + ((c*256 + kg*2) ^ ((c&7)<<4))) = v;
        }
        const u16* wlh = wl + (m&1)*4096;
        #pragma unroll
        for (int tix = 0; tix < 4; ++tix){
          int t = wid + tix*8;
          if (t < 26){
            int n = t >> 1, cb = t & 1;
            const u16* xb = xs + n*2048;
            f32x4 d = {0.f,0.f,0.f,0.f};
            #pragma unroll
            for (int kk = 0; kk < 4; ++kk){
              bf16x8 a = ldfrag(xb, lrow, kk*32 + lkg*8);
              bf16x8 b = ldfrag(wlh, cb*16 + lrow, kk*32 + lkg*8);
              d = MFMA16(a, b, d);
            }
            if (m == 0) kacc[tix] = d;
            else if (m == 3) sacc[tix] = d;
            else {
              int cl = cb*16 + lrow;
              #pragma unroll
              for (int i = 0; i < 4; ++i)
                qv[(m-1)*6656 + (n*16 + lkg*4 + i)*32 + cl] = f2bf(d[i]);
            }
          }
        }
        __syncthreads();
      }
      #pragma unroll
      for (int tix = 0; tix < 4; ++tix){
        int t = wid + tix*8;
        if (t < 26){
          int n = t >> 1, cb = t & 1;
          int cl = cb*16 + lrow, c = c0 + cl;
          float bkq = bf2f(bk[c]) + bf2f(bq[c]);
          float bvv = bf2f(bv[c]);
          float bss = bf2f(bs[c]);
          int cnt = nbr_cnt(n);
          #pragma unroll
          for (int i = 0; i < 4; ++i){
            int row = lkg*4 + i;
            float acc = sacc[tix][i] + bss;
            float kk_ = kacc[tix][i] + bkq;
            for (int e = 0; e < cnt; ++e){
              int s = nbr_of(n, e);
              float ql = bf2f(qv[(s*16 + row)*32 + cl]);
              float vl = bf2f(qv[6656 + (s*16 + row)*32 + cl]);
              acc += sigmf(kk_ + ql) * (vl + bvv);
            }
            st1_swz(hidB + n*2048, row, c, eluf(acc));
          }
        }
      }
      __syncthreads();
    }
  }

  {
    const u16* wt0 = Wt + TF.o[8];  const u16* wt1 = Wt + TF.o[9];
    const u16* wt2 = Wt + TF.o[10]; const u16* wt3 = Wt + TF.o[11];
    const u16* bk = Wb + O.o[25]; const u16* bq = Wb + O.o[27];
    const u16* bv = Wb + O.o[29]; const u16* bs = Wb + O.o[31];
    for (int c0 = 0; c0 < 64; c0 += 32){
      {
        int c = tid >> 4, kg = (tid & 15) << 3;
        uint4 v = *(const uint4*)(wt0 + (c0 + c)*128 + kg);
        *(uint4*)((char*)wl + ((c*256 + kg*2) ^ ((c&7)<<4))) = v;
      }
      __syncthreads();
      f32x4 kacc[4], sacc[4];
      #pragma unroll
      for (int m = 0; m < 4; ++m){
        if (m < 3){
          const u16* nxt = (m == 0) ? wt1 : (m == 1) ? wt2 : wt3;
          int c = tid >> 4, kg = (tid & 15) << 3;
          uint4 v = *(const uint4*)(nxt + (c0 + c)*128 + kg);
          *(uint4*)((char*)wl + (((m+1)&1)*8192) + ((c*256 + kg*2) ^ ((c&7)<<4))) = v;
        }
        const u16* wlh = wl + (m&1)*4096;
        #pragma unroll
        for (int tix = 0; tix < 4; ++tix){
          int t = wid + tix*8;
          if (t < 26){
            int n = t >> 1, cb = t & 1;
            const u16* xb = hidB + n*2048;
            f32x4 d = {0.f,0.f,0.f,0.f};
            #pragma unroll
            for (int kk = 0; kk < 4; ++kk){
              bf16x8 a = ldfrag(xb, lrow, kk*32 + lkg*8);
              bf16x8 b = ldfrag(wlh, cb*16 + lrow, kk*32 + lkg*8);
              d = MFMA16(a, b, d);
            }
            if (m == 0) kacc[tix] = d;
            else if (m == 3) sacc[tix] = d;
            else {
              int cl = cb*16 + lrow;
              #pragma unroll
              for (int i = 0; i < 4; ++i)
                qv[(m-1)*6656 + (n*16 + lkg*4 + i)*32 + cl] = f2bf(d[i]);
            }
          }
        }
        __syncthreads();
      }
      #pragma unroll
      for (int tix = 0; tix < 4; ++tix){
        int t = wid + tix*8;
        if (t < 26){
          int n = t >> 1, cb = t & 1;
          int cl = cb*16 + lrow, c = c0 + cl;
          float bkq = bf2f(bk[c]) + bf2f(bq[c]);
          float bvv = bf2f(bv[c]);
          float bss = bf2f(bs[c]);
          int cnt = nbr_cnt(n);
          #pragma unroll
          for (int i = 0; i < 4; ++i){
            int row = lkg*4 + i;
            float acc = sacc[tix][i] + bss;
            float kk_ = kacc[tix][i] + bkq;
            for (int e = 0; e < cnt; ++e){
              int s = nbr_of(n, e);
              float ql = bf2f(qv[(s*16 + row)*32 + cl]);
              float vl = bf2f(qv[6656 + (s*16 + row)*32 + cl]);
              acc += sigmf(kk_ + ql) * (vl + bvv);
            }
            xs[(n*16 + row)*128 + c] = f2bf(acc);
          }
        }
      }
      __syncthreads();
    }
  }

  for (int u = tid; u < 13*16*8; u += 512){
    int n = u >> 7, rem = u & 127, r = rem >> 3, j0 = (rem & 7) << 3;
    if (b0 + r < Btot)
      *(uint4*)(h2g + ((b0 + r)*13 + n)*64 + j0) = *(const uint4*)(xs + (n*16 + r)*128 + j0);
  }
}

// ========== K2-MFMA: leg MLP. 64 instances/block (16 rows x 4 legs) ==========
__global__ __launch_bounds__(512) void k2m(const u16* Wb, OffsT O, const u16* Wt, TOffs TF,
                                           const u16* h2g, float* out, int Btot){
  __shared__ u16 lat [64*256];     // 32768B swizzled (512B stride)
  __shared__ u16 a1s [64*256];     // 32768B swizzled
  __shared__ u16 a2s [64*128];     // 16384B swizzled (256B stride)
  __shared__ u16 wbuf[2][32*256];  // 32768B weight chunks (512B stride, swizzled)

  const int tid  = threadIdx.x;
  const int lane = tid & 63;
  const int wid  = tid >> 6;
  const int lrow = lane & 15;
  const int lkg  = lane >> 4;
  const int r0   = blockIdx.x * 16;
  const int mt   = wid >> 1, cb = wid & 1;   // per-wave M-tile / N-subtile

  // gather h2 -> lat (LEGS gather)
  for (int u = tid; u < 64*32; u += 512){
    int inst = u >> 5, k0 = (u & 31) << 3;
    int r = inst >> 2, g = inst & 3;
    int br = r0 + r; if (br >= Btot) br = Btot - 1;
    int seg = k0 >> 6, f = k0 & 63;
    int node = (seg == 0) ? 0 : (seg - 1)*4 + 1 + g;
    uint4 v = *(const uint4*)(h2g + (br*13 + node)*64 + f);
    *(uint4*)((char*)lat + ((inst*512 + k0*2) ^ ((inst&7)<<4))) = v;
  }
  const u16* w1t = Wt + TF.o[12];
  const u16* b1  = Wb + O.o[33];
  for (int u = tid; u < 1024; u += 512){
    int c = u >> 5, kg = (u & 31) << 3;
    uint4 v = *(const uint4*)(w1t + c*256 + kg);
    *(uint4*)((char*)wbuf[0] + ((c*512 + kg*2) ^ ((c&7)<<4))) = v;
  }
  __syncthreads();

  // a1 = elu(lat @ w1 + b1): 8 chunks of 32 cols, double-buffered weights
  for (int ch = 0; ch < 8; ++ch){
    if (ch < 7){
      for (int u = tid; u < 1024; u += 512){
        int c = u >> 5, kg = (u & 31) << 3;
        uint4 v = *(const uint4*)(w1t + ((ch+1)*32 + c)*256 + kg);
        *(uint4*)((char*)wbuf[(ch+1)&1] + ((c*512 + kg*2) ^ ((c&7)<<4))) = v;
      }
    }
    const u16* wb = wbuf[ch&1];
    f32x4 d = {0.f,0.f,0.f,0.f};
    #pragma unroll
    for (int kk = 0; kk < 8; ++kk){
      bf16x8 a = ldfrag5(lat, mt*16 + lrow, kk*32 + lkg*8);
      bf16x8 b = ldfrag5(wb,  cb*16 + lrow, kk*32 + lkg*8);
      d = MFMA16(a, b, d);
    }
    int col = ch*32 + cb*16 + lrow;
    float bvv = bf2f(b1[col]);
    #pragma unroll
    for (int i = 0; i < 4; ++i)
      st1_5(a1s, mt*16 + lkg*4 + i, col, eluf(d[i] + bvv));
    __syncthreads();
  }

  // a2 = elu(a1 @ w2 + b2): 4 chunks of 32 cols
  const u16* w2t = Wt + TF.o[13];
  const u16* b2  = Wb + O.o[35];
  for (int u = tid; u < 1024; u += 512){
    int c = u >> 5, kg = (u & 31) << 3;
    uint4 v = *(const uint4*)(w2t + c*256 + kg);
    *(uint4*)((char*)wbuf[0] + ((c*512 + kg*2) ^ ((c&7)<<4))) = v;
  }
  __syncthreads();
  for (int ch = 0; ch < 4; ++ch){
    if (ch < 3){
      for (int u = tid; u < 1024; u += 512){
        int c = u >> 5, kg = (u & 31) << 3;
        uint4 v = *(const uint4*)(w2t + ((ch+1)*32 + c)*256 + kg);
        *(uint4*)((char*)wbuf[(ch+1)&1] + ((c*512 + kg*2) ^ ((c&7)<<4))) = v;
      }
    }
    const u16* wb = wbuf[ch&1];
    f32x4 d = {0.f,0.f,0.f,0.f};
    #pragma unroll
    for (int kk = 0; kk < 8; ++kk){
      bf16x8 a = ldfrag5(a1s, mt*16 + lrow, kk*32 + lkg*8);
      bf16x8 b = ldfrag5(wb,  cb*16 + lrow, kk*32 + lkg*8);
      d = MFMA16(a, b, d);
    }
    int col = ch*32 + cb*16 + lrow;
    float bvv = bf2f(b2[col]);
    #pragma unroll
    for (int i = 0; i < 4; ++i)
      st1_swz(a2s, mt*16 + lkg*4 + i, col, eluf(d[i] + bvv));
    __syncthreads();
  }

  // out = a2 @ w3 + b3 (N=3, VALU)
  if (tid < 64*3){
    const u16* w3 = Wb + O.o[36], *b3 = Wb + O.o[37];
    int inst = tid / 3, c = tid % 3;
    int r = inst >> 2, g = inst & 3;
    float acc = bf2f(b3[c]);
    for (int k0 = 0; k0 < 128; k0 += 8){
      const u16* ap = (const u16*)((const char*)a2s + ((inst*256 + k0*2) ^ ((inst&7)<<4)));
      float av[8]; bf8(ap, av);
      #pragma unroll
      for (int jj = 0; jj < 8; ++jj) acc = fmaf(av[jj], bf2f(w3[(k0+jj)*3 + c]), acc);
    }
    if (r0 + r < Btot) out[(r0 + r)*12 + g*3 + c] = acc;
  }
}

// ================= fallback: R7 monolithic kernel (proven) =================
#define TPB 512
#define RR  6
__global__ __launch_bounds__(TPB) void actor_v2(PtrTab T, const int* flg, float* out, int Btot){
  __shared__ float A [RR][13][132];
  __shared__ float Bf[RR][13][132];
  __shared__ u16   Cq[3][RR][13][128];
  __shared__ float obs_s[RR][111];
  __shared__ int   fls[NIN];

  const int tid = threadIdx.x;
  const int b0  = blockIdx.x * RR;

  if (tid < NIN){ int j = (tid >= 3 && (tid & 1)) ? tid - 1 : tid; fls[tid] = flg[j]; }
  __syncthreads();
  const bool BFobs = fls[0] != 0, BFlat = fls[1] != 0;

  for (int u = tid; u < RR * 111; u += TPB){
    int r = u / 111, c = u % 111;
    int br = b0 + r; if (br >= Btot) br = Btot - 1;
    obs_s[r][c] = ldv(T.p[0], br * 111 + c, BFobs);
  }
  __syncthreads();

  for (int u = tid; u < RR * 13 * 16; u += TPB){
    int r = u / 208, rem = u % 208, n = rem >> 4, h0 = (rem & 15) << 3;
    int ty  = (n == 0) ? 0 : (n <= 4) ? 1 : (n <= 8) ? 2 : 3;
    int off = (n == 0) ? 0 : (ty == 1) ? 15 + 24 * (n - 1)
             : (ty == 2) ? 15 + 24 * (n - 5) + 8 : 15 + 24 * (n - 9) + 16;
    int K = (n == 0) ? 15 : 8;
    const void* w1 = T.p[2 + 4 * ty];
    bool bw = fls[2 + 4 * ty] != 0, bb = fls[3 + 4 * ty] != 0;
    float acc8[8]; ld8(T.p[3 + 4 * ty], h0, bb, acc8);
    for (int k = 0; k < K; ++k){
      float xv = obs_s[r][off + k];
      float wf[8]; ld8(w1, k * 128 + h0, bw, wf);
      #pragma unroll
      for (int jj = 0; jj < 8; ++jj) acc8[jj] = fmaf(xv, wf[jj], acc8[jj]);
    }
    #pragma unroll
    for (int jj = 0; jj < 8; ++jj) Bf[r][n][h0 + jj] = eluf(acc8[jj]);
  }
  __syncthreads();

  for (int u = tid; u < 13 * 8; u += TPB){
    int n = u >> 3, o0 = (u & 7) << 3;
    int ty = (n == 0) ? 0 : (n <= 4) ? 1 : (n <= 8) ? 2 : 3;
    const void* w2 = T.p[4 + 4 * ty];
    bool bw = fls[4 + 4 * ty] != 0, bb = fls[5 + 4 * ty] != 0;
    float bv[8]; ld8(T.p[5 + 4 * ty], o0, bb, bv);
    float acc[RR][8];
    #pragma unroll
    for (int r = 0; r < RR; ++r)
      #pragma unroll
      for (int jj = 0; jj < 8; ++jj) acc[r][jj] = bv[jj];
    #pragma unroll 4
    for (int k = 0; k < 128; ++k){
      float wf[8]; ld8(w2, k * 64 + o0, bw, wf);
      #pragma unroll
      for (int r = 0; r < RR; ++r){
        float xv = Bf[r][n][k];
        #pragma unroll
        for (int jj = 0; jj < 8; ++jj) acc[r][jj] = fmaf(xv, wf[jj], acc[r][jj]);
      }
    }
    #pragma unroll
    for (int r = 0; r < RR; ++r)
      #pragma unroll
      for (int jj = 0; jj < 8; ++jj) A[r][n][o0 + jj] = acc[r][jj];
  }
  for (int u = tid; u < RR * 13 * 8; u += TPB){
    int r = u / 104, rem = u % 104, n = rem >> 3, j0 = (rem & 7) << 3;
    int br = b0 + r; if (br >= Btot) br = Btot - 1;
    float lv[8]; ld8(T.p[1], (br * 13 + n) * 64 + j0, BFlat, lv);
    #pragma unroll
    for (int jj = 0; jj < 8; ++jj) A[r][n][64 + j0 + jj] = lv[jj];
  }
  __syncthreads();

  for (int u = tid; u < 4 * 13 * 16; u += TPB){
    int mat = u / 208, rem = u % 208, n = rem >> 4, j0 = (rem & 15) << 3;
    const void* W = T.p[18 + 2 * mat];
    bool bw = fls[18 + 2 * mat] != 0, bb = fls[19 + 2 * mat] != 0;
    float bv[8]; ld8(T.p[19 + 2 * mat], j0, bb, bv);
    float acc[RR][8];
    #pragma unroll
    for (int r = 0; r < RR; ++r)
      #pragma unroll
      for (int jj = 0; jj < 8; ++jj) acc[r][jj] = bv[jj];
    #pragma unroll 4
    for (int k = 0; k < 128; ++k){
      float wf[8]; ld8(W, k * 128 + j0, bw, wf);
      #pragma unroll
      for (int r = 0; r < RR; ++r){
        float xv = A[r][n][k];
        #pragma unroll
        for (int jj = 0; jj < 8; ++jj) acc[r][jj] = fmaf(xv, wf[jj], acc[r][jj]);
      }
    }
    if (mat < 3){
      #pragma unroll
      for (int r = 0; r < RR; ++r) st8bf(&Cq[mat][r][n][j0], acc[r]);
    } else {
      #pragma unroll
      for (int r = 0; r < RR; ++r)
        #pragma unroll
        for (int jj = 0; jj < 8; ++jj) Bf[r][n][j0 + jj] = acc[r][jj];
    }
  }
  __syncthreads();

  for (int u = tid; u < RR * 13 * 16; u += TPB){
    int r = u / 208, rem = u % 208, n = rem >> 4, j0 = (rem & 15) << 3;
    float acc8[8];
    #pragma unroll
    for (int jj = 0; jj < 8; ++jj) acc8[jj] = Bf[r][n][j0 + jj];
    float k8[8]; bf8(&Cq[0][r][n][j0], k8);
    int cnt = nbr_cnt(n);
    for (int e = 0; e < cnt; ++e){
      int s = nbr_of(n, e);
      float q8[8], v8[8];
      bf8(&Cq[1][r][s][j0], q8);
      bf8(&Cq[2][r][s][j0], v8);
      #pragma unroll
      for (int jj = 0; jj < 8; ++jj) acc8[jj] = fmaf(sigmf(k8[jj] + q8[jj]), v8[jj], acc8[jj]);
    }
    #pragma unroll
    for (int jj = 0; jj < 8; ++jj) Bf[r][n][j0 + jj] = eluf(acc8[jj]);
  }
  __syncthreads();

  for (int u = tid; u < 4 * 13 * 8; u += TPB){
    int mat = u / 104, rem = u % 104, n = rem >> 3, j0 = (rem & 7) << 3;
    const void* W = T.p[26 + 2 * mat];
    bool bw = fls[26 + 2 * mat] != 0, bb = fls[27 + 2 * mat] != 0;
    float bv[8]; ld8(T.p[27 + 2 * mat], j0, bb, bv);
    float acc[RR][8];
    #pragma unroll
    for (int r = 0; r < RR; ++r)
      #pragma unroll
      for (int jj = 0; jj < 8; ++jj) acc[r][jj] = bv[jj];
    #pragma unroll 4
    for (int k = 0; k < 128; ++k){
      float wf[8]; ld8(W, k * 64 + j0, bw, wf);
      #pragma unroll
      for (int r = 0; r < RR; ++r){
        float xv = Bf[r][n][k];
        #pragma unroll
        for (int jj = 0; jj < 8; ++jj) acc[r][jj] = fmaf(xv, wf[jj], acc[r][jj]);
      }
    }
    if (mat < 3){
      #pragma unroll
      for (int r = 0; r < RR; ++r) st8bf(&Cq[mat][r][n][j0], acc[r]);
    } else {
      #pragma unroll
      for (int r = 0; r < RR; ++r)
        #pragma unroll
        for (int jj = 0; jj < 8; ++jj) A[r][n][j0 + jj] = acc[r][jj];
    }
  }
  __syncthreads();

  for (int u = tid; u < RR * 13 * 8; u += TPB){
    int r = u / 104, rem = u % 104, n = rem >> 3, j0 = (rem & 7) << 3;
    float acc8[8];
    #pragma unroll
    for (int jj = 0; jj < 8; ++jj) acc8[jj] = A[r][n][j0 + jj];
    float k8[8]; bf8(&Cq[0][r][n][j0], k8);
    int cnt = nbr_cnt(n);
    for (int e = 0; e < cnt; ++e){
      int s = nbr_of(n, e);
      float q8[8], v8[8];
      bf8(&Cq[1][r][s][j0], q8);
      bf8(&Cq[2][r][s][j0], v8);
      #pragma unroll
      for (int jj = 0; jj < 8; ++jj) acc8[jj] = fmaf(sigmf(k8[jj] + q8[jj]), v8[jj], acc8[jj]);
    }
    #pragma unroll
    for (int jj = 0; jj < 8; ++jj) A[r][n][j0 + jj] = acc8[jj];
  }
  __syncthreads();

  float* a1f = (float*)&Cq[0][0][0][0];
  float* a2f = (float*)&Bf[0][0][0];
  {
    bool bw = fls[34] != 0, bb = fls[35] != 0;
    for (int u = tid; u < 6 * 32; u += TPB){
      int iq = u >> 5, j0 = (u & 31) << 3;
      float bv[8]; ld8(T.p[35], j0, bb, bv);
      float acc[4][8];
      #pragma unroll
      for (int t = 0; t < 4; ++t)
        #pragma unroll
        for (int jj = 0; jj < 8; ++jj) acc[t][jj] = bv[jj];
      #pragma unroll 2
      for (int k = 0; k < 256; ++k){
        float wf[8]; ld8(T.p[34], k * 256 + j0, bw, wf);
        int seg = k >> 6, f = k & 63;
        #pragma unroll
        for (int t = 0; t < 4; ++t){
          int inst = iq * 4 + t, r = inst >> 2, g = inst & 3;
          int node = (seg == 0) ? 0 : (seg - 1) * 4 + 1 + g;
          float xv = A[r][node][f];
          #pragma unroll
          for (int jj = 0; jj < 8; ++jj) acc[t][jj] = fmaf(xv, wf[jj], acc[t][jj]);
        }
      }
      #pragma unroll
      for (int t = 0; t < 4; ++t){
        int inst = iq * 4 + t;
        #pragma unroll
        for (int jj = 0; jj < 8; ++jj) a1f[inst * 256 + j0 + jj] = eluf(acc[t][jj]);
      }
    }
  }
  __syncthreads();
  {
    bool bw = fls[36] != 0, bb = fls[37] != 0;
    for (int u = tid; u < 6 * 16; u += TPB){
      int iq = u >> 4, j0 = (u & 15) << 3;
      float bv[8]; ld8(T.p[37], j0, bb, bv);
      float acc[4][8];
      #pragma unroll
      for (int t = 0; t < 4; ++t)
        #pragma unroll
        for (int jj = 0; jj < 8; ++jj) acc[t][jj] = bv[jj];
      #pragma unroll 2
      for (int k = 0; k < 256; ++k){
        float wf[8]; ld8(T.p[36], k * 128 + j0, bw, wf);
        #pragma unroll
        for (int t = 0; t < 4; ++t){
          float xv = a1f[(iq * 4 + t) * 256 + k];
          #pragma unroll
          for (int jj = 0; jj < 8; ++jj) acc[t][jj] = fmaf(xv, wf[jj], acc[t][jj]);
        }
      }
      #pragma unroll
      for (int t = 0; t < 4; ++t){
        int inst = iq * 4 + t;
        #pragma unroll
        for (int jj = 0; jj < 8; ++jj) a2f[inst * 128 + j0 + jj] = eluf(acc[t][jj]);
      }
    }
  }
  __syncthreads();
  if (tid < RR * 4 * 3){
    int inst = tid / 3, c = tid % 3;
    int r = inst >> 2, g = inst & 3;
    bool bw = fls[38] != 0, bb = fls[39] != 0;
    float acc = ldv(T.p[39], c, bb);
    for (int k = 0; k < 128; ++k) acc = fmaf(a2f[inst * 128 + k], ldv(T.p[38], k * 3 + c, bw), acc);
    if (b0 + r < Btot) out[(b0 + r) * 12 + g * 3 + c] = acc;
  }
}

extern "C" void kernel_launch(void* const* d_in, const int* in_sizes, int n_in,
                              void* d_out, int out_size, void* d_ws, size_t ws_size,
                              hipStream_t stream){
  (void)out_size;
  PtrTab T;
  for (int i = 0; i < NIN; ++i){
    T.p[i] = (i < n_in) ? d_in[i] : d_in[0];
    T.n[i] = (i < n_in) ? in_sizes[i] : 1;
  }
  int* fl = (int*)d_ws;
  hipLaunchKernelGGL(probe_kernel, dim3(NIN), dim3(256), 0, stream, T, fl);

  int Btot = T.n[0] / 111;

  OffsT O;
  size_t acc = 0;
  for (int s = 0; s < 38; ++s){
    O.o[s] = (int)acc;
    acc += ((size_t)T.n[s + 2] + 7) & ~(size_t)7;
  }
  static const int KK[14] = {128,128,128,128, 128,128,128,128, 128,128,128,128, 256,256};
  static const int NNm[14]= {64,64,64,64, 128,128,128,128, 64,64,64,64, 256,128};
  TOffs TF;
  int wtElems = 0;
  for (int m = 0; m < 14; ++m){ TF.o[m] = wtElems; wtElems += KK[m]*NNm[m]; }

  size_t wtoff = ((256 + acc * 2 + 511) / 512) * 512;
  size_t h2off = ((wtoff + (size_t)wtElems * 2 + 511) / 512) * 512;
  size_t need  = h2off + (size_t)Btot * 832 * 2;

  if (ws_size >= need){
    u16* Wb  = (u16*)((char*)d_ws + 256);
    u16* Wt  = (u16*)((char*)d_ws + wtoff);
    u16* h2g = (u16*)((char*)d_ws + h2off);
    hipLaunchKernelGGL(convert_kernel, dim3(38), dim3(256), 0, stream, T, fl, Wb, O);
    hipLaunchKernelGGL(transpose_kernel, dim3(14), dim3(256), 0, stream, Wb, O, Wt, TF);
    hipLaunchKernelGGL(k1m, dim3((unsigned)((Btot + 15) / 16)), dim3(512), 0, stream,
                       T, fl, Wb, O, Wt, TF, h2g, Btot);
    hipLaunchKernelGGL(k2m, dim3((unsigned)((Btot + 15) / 16)), dim3(512), 0, stream,
                       Wb, O, Wt, TF, h2g, (float*)d_out, Btot);
  } else {
    hipLaunchKernelGGL(actor_v2, dim3((unsigned)((Btot + RR - 1) / RR)), dim3(TPB), 0, stream,
                       T, fl, (float*)d_out, Btot);
  }
}